// Round 12
// baseline (804.052 us; speedup 1.0000x reference)
//
#include <hip/hip_runtime.h>
#include <hip/hip_cooperative_groups.h>

namespace cg = cooperative_groups;

#define Tt 2048
#define Cc 512
#define Bb 4
#define BC (Bb * Cc)
#define LSTR 72

typedef __attribute__((ext_vector_type(4))) float f32x4;
typedef __attribute__((ext_vector_type(8))) _Float16 f16x8;
typedef __attribute__((ext_vector_type(4))) _Float16 f16x4;
typedef __attribute__((ext_vector_type(2))) _Float16 f16x2;

// async global->LDS 16B copy: dest = wave-uniform LDS base + lane*16.
__device__ static inline void gl16(const _Float16* g, _Float16* l)
{
    __builtin_amdgcn_global_load_lds(
        (const __attribute__((address_space(1))) void*)g,
        (__attribute__((address_space(3))) void*)l, 16, 0, 0);
}

// ---------------------------------------------------------------------------
// Mega-kernel: 4 phases in one cooperative dispatch (phase=-1) or single
// phase per regular dispatch (phase=0..3, fallback if coop launch fails).
// Phase 0: prep (HS->fp16, W->Wt, colsum zero)   [2307 chunks over 768 blk]
// Phase 1: qkv GEMM + V->VT transpose epilogue   [768 blocks]
// Phase 2: flash attention                       [blocks < 512]
// Phase 3: out GEMM + bias + residual            [blocks < 512]
// Grid 768 = 3 blocks/CU co-resident (LDS 36.9KB -> 4/CU; VGPR capped by
// launch_bounds(256,3)). grid.sync + threadfence between phases.
// ---------------------------------------------------------------------------
__global__ __launch_bounds__(256, 3) void mega(
    const float* Wq, const float* Wk, const float* Wv, const float* Wo,
    const float* HS, const float* bo, float* outp,
    _Float16* Qf, _Float16* Kf, _Float16* VTh, _Float16* HSh,
    _Float16* AO, _Float16* Wt, float* colsum, int phase)
{
    __shared__ __align__(16) char smem_raw[36864];
    const int bid = threadIdx.y + blockIdx.x;   // threadIdx.y==0; keeps bid in sgpr path
    const int tid = threadIdx.x;
    const bool all = (phase < 0);

    // ================= phase 0: prep =================
    if (all || phase == 0) {
        float* tile = (float*)smem_raw;          // [64][65] floats (16.6 KB)
        for (int blk = bid; blk < 2307; blk += 768) {
            __syncthreads();
            if (blk < 2048) {
                const size_t i = ((size_t)blk * 256 + tid) * 8;
                float4 a = *(const float4*)&HS[i];
                float4 b = *(const float4*)&HS[i + 4];
                f16x8 o;
                o[0] = (_Float16)a.x; o[1] = (_Float16)a.y;
                o[2] = (_Float16)a.z; o[3] = (_Float16)a.w;
                o[4] = (_Float16)b.x; o[5] = (_Float16)b.y;
                o[6] = (_Float16)b.z; o[7] = (_Float16)b.w;
                *(f16x8*)&HSh[i] = o;
            } else if (blk < 2304) {
                const int lb = blk - 2048;
                const int z = lb >> 6, x = lb & 63;
                const float* W = (z == 0) ? Wq : (z == 1) ? Wk : (z == 2) ? Wv : Wo;
                const int k0 = (x >> 3) * 64, n0 = (x & 7) * 64;
#pragma unroll
                for (int i = 0; i < 4; ++i) {
                    const int idx = i * 256 + tid;
                    const int kr = idx >> 4, c4 = idx & 15;
                    float4 v = *(const float4*)&W[(size_t)(k0 + kr) * Cc + n0 + c4 * 4];
                    tile[kr * 65 + c4 * 4 + 0] = v.x; tile[kr * 65 + c4 * 4 + 1] = v.y;
                    tile[kr * 65 + c4 * 4 + 2] = v.z; tile[kr * 65 + c4 * 4 + 3] = v.w;
                }
                __syncthreads();
#pragma unroll
                for (int i = 0; i < 4; ++i) {
                    const int idx = i * 256 + tid;
                    const int nr = idx >> 4, k4 = idx & 15;
                    f16x4 o;
                    o[0] = (_Float16)tile[(k4 * 4 + 0) * 65 + nr];
                    o[1] = (_Float16)tile[(k4 * 4 + 1) * 65 + nr];
                    o[2] = (_Float16)tile[(k4 * 4 + 2) * 65 + nr];
                    o[3] = (_Float16)tile[(k4 * 4 + 3) * 65 + nr];
                    *(f16x4*)&Wt[((size_t)(z * 512 + n0 + nr)) * Cc + k0 + k4 * 4] = o;
                }
            } else {
                const int i = (blk - 2304) * 2048 + tid * 8;
                *(f32x4*)&colsum[i]     = (f32x4){0.f, 0.f, 0.f, 0.f};
                *(f32x4*)&colsum[i + 4] = (f32x4){0.f, 0.f, 0.f, 0.f};
            }
        }
    }

    if (all) { __threadfence(); cg::this_grid().sync(); __threadfence(); }

    // ================= phase 1: qkv GEMM =================
    if (all || phase == 1) {
        const int z = bid >> 8, nt = (bid >> 6) & 3, mt = bid & 63;
        const int wave = tid >> 6, lane = tid & 63;
        const int quad = lane >> 4, lm = lane & 15;
        const int wm = (wave & 1) * 64, wn = (wave >> 1) * 64;

        _Float16* smem = (_Float16*)smem_raw;    // 128*136 halves used
        _Float16* sA = smem;                     // 128*32
        _Float16* sB = smem + 128 * 32;          // 128*32

        f32x4 acc[4][4];
#pragma unroll
        for (int mf = 0; mf < 4; ++mf)
#pragma unroll
            for (int nf = 0; nf < 4; ++nf) acc[mf][nf] = (f32x4){0.f, 0.f, 0.f, 0.f};

        const int lr = lane >> 2;
        const int lc = (lane & 3) * 8;
        const _Float16* gaA = HSh + (size_t)(mt * 128 + wave * 32 + lr) * Cc + lc;
        const _Float16* gaB = Wt + ((size_t)(z * 512 + nt * 128 + wave * 32 + lr)) * Cc + lc;
        _Float16* ldA = &sA[wave * 1024];
        _Float16* ldB = &sB[wave * 1024];

        for (int k0 = 0; k0 < Cc; k0 += 32) {
            __syncthreads();
            gl16(gaA + k0,            ldA);
            gl16(gaA + 16 * Cc + k0,  ldA + 512);
            gl16(gaB + k0,            ldB);
            gl16(gaB + 16 * Cc + k0,  ldB + 512);
            __syncthreads();

            f16x8 ah[4], bh[4];
#pragma unroll
            for (int mf = 0; mf < 4; ++mf)
                ah[mf] = *(const f16x8*)&sA[(wm + mf * 16 + lm) * 32 + quad * 8];
#pragma unroll
            for (int nf = 0; nf < 4; ++nf)
                bh[nf] = *(const f16x8*)&sB[(wn + nf * 16 + lm) * 32 + quad * 8];
#pragma unroll
            for (int mf = 0; mf < 4; ++mf)
#pragma unroll
                for (int nf = 0; nf < 4; ++nf)
                    acc[mf][nf] = __builtin_amdgcn_mfma_f32_16x16x32_f16(ah[mf], bh[nf], acc[mf][nf], 0, 0, 0);
        }

        const int bidx = mt >> 4;
        _Float16* Out = (z == 0) ? Qf : Kf;
#pragma unroll
        for (int nf = 0; nf < 4; ++nf) {
            float cs = 0.f;
#pragma unroll
            for (int mf = 0; mf < 4; ++mf)
#pragma unroll
                for (int r = 0; r < 4; ++r) {
                    const float v = acc[mf][nf][r];
                    cs += v * v;
                    if (z < 2) {
                        const size_t idx =
                            (size_t)(mt * 128 + wm + mf * 16 + quad * 4 + r) * Cc +
                            nt * 128 + wn + nf * 16 + lm;
                        Out[idx] = (_Float16)v;
                    }
                }
            cs += __shfl_xor(cs, 16, 64);
            cs += __shfl_xor(cs, 32, 64);
            if (lane < 16)
                atomicAdd(&colsum[(size_t)z * BC + bidx * Cc + nt * 128 + wn + nf * 16 + lane], cs);
        }

        if (z == 2) {
            __syncthreads();
#pragma unroll
            for (int nf = 0; nf < 4; ++nf) {
                const int c = wn + nf * 16 + lm;
#pragma unroll
                for (int mf = 0; mf < 4; ++mf) {
                    const int m0 = wm + mf * 16 + quad * 4;
                    const int tl = m0 & 63;
                    const int u = tl >> 3, j0 = tl & 7;
                    const int p0 = ((u >> 2) & 1) * 32 + (u & 1) * 16 +
                                   ((u >> 1) & 1) * 4 + ((j0 >= 4) ? 8 : 0);
                    const int tperm = (m0 & 64) + p0;
                    f16x4 pk;
#pragma unroll
                    for (int r = 0; r < 4; ++r) pk[r] = (_Float16)acc[mf][nf][r];
                    *(f16x4*)&smem[c * 136 + tperm] = pk;
                }
            }
            __syncthreads();
            const int b = mt >> 4;
            const int tbase = (mt & 15) * 128;
#pragma unroll
            for (int i = 0; i < 8; ++i) {
                const int idx = i * 256 + tid;
                const int cr = idx >> 4, t8 = (idx & 15) * 8;
                f16x8 v = *(const f16x8*)&smem[cr * 136 + t8];
                *(f16x8*)&VTh[((size_t)(b * Cc) + nt * 128 + cr) * Tt + tbase + t8] = v;
            }
        }
    }

    if (all) { __threadfence(); cg::this_grid().sync(); __threadfence(); }

    // ================= phase 2: flash attention =================
    if ((all || phase == 2) && bid < 512) {
        const int qt = bid >> 5;
        const int bh = bid & 31;
        const int b = bh >> 3, h = bh & 7;
        const int wave = tid >> 6, lane = tid & 63;
        const int quad = lane >> 4, lm = lane & 15;
        const float invT = 1.0f / Tt;

        _Float16* sKb = (_Float16*)smem_raw;         // 2 * 4608 halves
        _Float16* sVb = sKb + 2 * 64 * LSTR;         // 2 * 4608 halves

        float ss[2][8];
        {
            const float* csq = colsum + b * Cc + h * 64;
            const float* csk = colsum + BC + b * Cc + h * 64;
#pragma unroll
            for (int ks = 0; ks < 2; ++ks) {
                const int d0 = ks * 32 + quad * 8;
#pragma unroll
                for (int j = 0; j < 8; ++j) {
                    const float iq = rsqrtf(csq[d0 + j] * invT + 1e-4f);
                    const float ik = rsqrtf(csk[d0 + j] * invT + 1e-4f);
                    ss[ks][j] = iq * ik * 0.18033688011f;
                }
            }
        }

        f16x8 qb[2][2];
        {
#pragma unroll
            for (int qf = 0; qf < 2; ++qf) {
                const int row = qt * 128 + wave * 32 + qf * 16 + lm;
#pragma unroll
                for (int ks = 0; ks < 2; ++ks) {
                    const int d0 = ks * 32 + quad * 8;
                    f16x8 qv = *(const f16x8*)&Qf[(size_t)(b * Tt + row) * Cc + h * 64 + d0];
#pragma unroll
                    for (int j = 0; j < 8; ++j)
                        qb[qf][ks][j] = (_Float16)((float)qv[j] * ss[ks][j]);
                }
            }
        }

        f32x4 o[4][2];
#pragma unroll
        for (int cf = 0; cf < 4; ++cf)
#pragma unroll
            for (int qf = 0; qf < 2; ++qf) o[cf][qf] = (f32x4){0.f, 0.f, 0.f, 0.f};
        f32x4 ol[2];
#pragma unroll
        for (int qf = 0; qf < 2; ++qf) ol[qf] = (f32x4){0.f, 0.f, 0.f, 0.f};
        f16x8 ones;
#pragma unroll
        for (int j = 0; j < 8; ++j) ones[j] = (_Float16)1.0f;

        f16x8 pb[2][2];
#pragma unroll
        for (int qf = 0; qf < 2; ++qf)
#pragma unroll
            for (int ks = 0; ks < 2; ++ks)
#pragma unroll
                for (int j = 0; j < 8; ++j) pb[qf][ks][j] = (_Float16)0.0f;

        const int sr0 = tid >> 3, sc0 = (tid & 7) * 8;
        const int sr1 = sr0 + 32;
        const _Float16* gK = Kf + (size_t)b * Tt * Cc + h * 64;
        const _Float16* gV = VTh + ((size_t)b * Cc + h * 64) * Tt;

        f16x8 rk0, rk1, rv0, rv1;
        {
            rk0 = *(const f16x8*)&gK[(size_t)sr0 * Cc + sc0];
            rk1 = *(const f16x8*)&gK[(size_t)sr1 * Cc + sc0];
            rv0 = *(const f16x8*)&gV[(size_t)sr0 * Tt + sc0];
            rv1 = *(const f16x8*)&gV[(size_t)sr1 * Tt + sc0];
        }

#pragma unroll 2
        for (int kt = 0; kt < 32; ++kt) {
            const int cur = kt & 1, prv = cur ^ 1;
            _Float16* sKc = sKb + cur * (64 * LSTR);
            _Float16* sVc = sVb + cur * (64 * LSTR);

            __syncthreads();
            *(f16x8*)&sKc[sr0 * LSTR + sc0] = rk0;
            *(f16x8*)&sKc[sr1 * LSTR + sc0] = rk1;
            *(f16x8*)&sVc[sr0 * LSTR + sc0] = rv0;
            *(f16x8*)&sVc[sr1 * LSTR + sc0] = rv1;
            __syncthreads();

            if (kt < 31) {
                const int t0 = (kt + 1) * 64;
                rk0 = *(const f16x8*)&gK[(size_t)(t0 + sr0) * Cc + sc0];
                rk1 = *(const f16x8*)&gK[(size_t)(t0 + sr1) * Cc + sc0];
                rv0 = *(const f16x8*)&gV[(size_t)sr0 * Tt + t0 + sc0];
                rv1 = *(const f16x8*)&gV[(size_t)sr1 * Tt + t0 + sc0];
            }

            // ---- S^T(kt) = K Q^T
            f32x4 st[4][2];
#pragma unroll
            for (int kf = 0; kf < 4; ++kf)
#pragma unroll
                for (int qf = 0; qf < 2; ++qf) st[kf][qf] = (f32x4){0.f, 0.f, 0.f, 0.f};
#pragma unroll
            for (int ks = 0; ks < 2; ++ks) {
                f16x8 ka[4];
#pragma unroll
                for (int kf = 0; kf < 4; ++kf)
                    ka[kf] = *(const f16x8*)&sKc[(kf * 16 + lm) * LSTR + ks * 32 + quad * 8];
                __builtin_amdgcn_s_setprio(1);
#pragma unroll
                for (int kf = 0; kf < 4; ++kf)
#pragma unroll
                    for (int qf = 0; qf < 2; ++qf)
                        st[kf][qf] = __builtin_amdgcn_mfma_f32_16x16x32_f16(ka[kf], qb[qf][ks], st[kf][qf], 0, 0, 0);
                __builtin_amdgcn_s_setprio(0);
            }

            // ---- PV(kt-1)
            if (kt > 0) {
                _Float16* sVp = sVb + prv * (64 * LSTR);
#pragma unroll
                for (int ks = 0; ks < 2; ++ks) {
                    f16x8 va[4];
#pragma unroll
                    for (int cf = 0; cf < 4; ++cf)
                        va[cf] = *(const f16x8*)&sVp[(cf * 16 + lm) * LSTR + ks * 32 + quad * 8];
                    __builtin_amdgcn_s_setprio(1);
#pragma unroll
                    for (int cf = 0; cf < 4; ++cf)
#pragma unroll
                        for (int qf = 0; qf < 2; ++qf)
                            o[cf][qf] = __builtin_amdgcn_mfma_f32_16x16x32_f16(va[cf], pb[qf][ks], o[cf][qf], 0, 0, 0);
#pragma unroll
                    for (int qf = 0; qf < 2; ++qf)
                        ol[qf] = __builtin_amdgcn_mfma_f32_16x16x32_f16(ones, pb[qf][ks], ol[qf], 0, 0, 0);
                    __builtin_amdgcn_s_setprio(0);
                }
            }

            // ---- p = exp2(s(kt)) -> pb regs
#pragma unroll
            for (int ks = 0; ks < 2; ++ks)
#pragma unroll
                for (int qf = 0; qf < 2; ++qf) {
                    const f32x4 a = st[2 * ks][qf];
                    const f32x4 c = st[2 * ks + 1][qf];
                    const f16x2 l0 = __builtin_bit_cast(f16x2, __builtin_amdgcn_cvt_pkrtz(
                        __builtin_amdgcn_exp2f(a[0]), __builtin_amdgcn_exp2f(a[1])));
                    const f16x2 l1 = __builtin_bit_cast(f16x2, __builtin_amdgcn_cvt_pkrtz(
                        __builtin_amdgcn_exp2f(a[2]), __builtin_amdgcn_exp2f(a[3])));
                    const f16x2 h0 = __builtin_bit_cast(f16x2, __builtin_amdgcn_cvt_pkrtz(
                        __builtin_amdgcn_exp2f(c[0]), __builtin_amdgcn_exp2f(c[1])));
                    const f16x2 h1 = __builtin_bit_cast(f16x2, __builtin_amdgcn_cvt_pkrtz(
                        __builtin_amdgcn_exp2f(c[2]), __builtin_amdgcn_exp2f(c[3])));
                    f16x8 p;
                    p[0] = l0[0]; p[1] = l0[1]; p[2] = l1[0]; p[3] = l1[1];
                    p[4] = h0[0]; p[5] = h0[1]; p[6] = h1[0]; p[7] = h1[1];
                    pb[qf][ks] = p;
                }
        }

        // ---- drain PV(31)
        {
            _Float16* sVp = sVb + 64 * LSTR;
#pragma unroll
            for (int ks = 0; ks < 2; ++ks) {
                f16x8 va[4];
#pragma unroll
                for (int cf = 0; cf < 4; ++cf)
                    va[cf] = *(const f16x8*)&sVp[(cf * 16 + lm) * LSTR + ks * 32 + quad * 8];
#pragma unroll
                for (int cf = 0; cf < 4; ++cf)
#pragma unroll
                    for (int qf = 0; qf < 2; ++qf)
                        o[cf][qf] = __builtin_amdgcn_mfma_f32_16x16x32_f16(va[cf], pb[qf][ks], o[cf][qf], 0, 0, 0);
#pragma unroll
                for (int qf = 0; qf < 2; ++qf)
                    ol[qf] = __builtin_amdgcn_mfma_f32_16x16x32_f16(ones, pb[qf][ks], ol[qf], 0, 0, 0);
            }
        }

        // ---- epilogue
        float il[2];
#pragma unroll
        for (int qf = 0; qf < 2; ++qf) il[qf] = 1.0f / ol[qf][0];
        const float* csv = colsum + 2 * BC + b * Cc + h * 64;
        float iv[4][4];
#pragma unroll
        for (int cf = 0; cf < 4; ++cf) {
            float4 t = *(const float4*)&csv[cf * 16 + quad * 4];
            iv[cf][0] = rsqrtf(t.x * invT + 1e-4f);
            iv[cf][1] = rsqrtf(t.y * invT + 1e-4f);
            iv[cf][2] = rsqrtf(t.z * invT + 1e-4f);
            iv[cf][3] = rsqrtf(t.w * invT + 1e-4f);
        }
#pragma unroll
        for (int qf = 0; qf < 2; ++qf) {
            const size_t row = (size_t)(b * Tt + qt * 128 + wave * 32 + qf * 16 + lm);
#pragma unroll
            for (int cf = 0; cf < 4; ++cf) {
                f16x4 pk;
#pragma unroll
                for (int r = 0; r < 4; ++r)
                    pk[r] = (_Float16)(o[cf][qf][r] * il[qf] * iv[cf][r]);
                *(f16x4*)&AO[row * Cc + h * 64 + cf * 16 + quad * 4] = pk;
            }
        }
    }

    if (all) { __threadfence(); cg::this_grid().sync(); __threadfence(); }

    // ================= phase 3: out GEMM =================
    if ((all || phase == 3) && bid < 512) {
        const int mt = bid & 127, nt = bid >> 7;
        const int wave = tid >> 6, lane = tid & 63;
        const int quad = lane >> 4, lm = lane & 15;
        const int wm = (wave & 1) * 32, wn = (wave >> 1) * 64;

        _Float16* oA = (_Float16*)smem_raw;      // 64*32 halves
        _Float16* oB = oA + 64 * 32;             // 128*32 halves

        f32x4 acc[2][4];
#pragma unroll
        for (int mf = 0; mf < 2; ++mf)
#pragma unroll
            for (int nf = 0; nf < 4; ++nf) acc[mf][nf] = (f32x4){0.f, 0.f, 0.f, 0.f};

        const int lr = lane >> 2;
        const int lc = (lane & 3) * 8;
        const _Float16* gaA = AO + (size_t)(mt * 64 + wave * 16 + lr) * Cc + lc;
        const _Float16* gaB = Wt + ((size_t)(3 * 512 + nt * 128 + wave * 32 + lr)) * Cc + lc;
        _Float16* ldA = &oA[wave * 512];
        _Float16* ldB = &oB[wave * 1024];

        for (int k0 = 0; k0 < Cc; k0 += 32) {
            __syncthreads();
            gl16(gaA + k0,           ldA);
            gl16(gaB + k0,           ldB);
            gl16(gaB + 16 * Cc + k0, ldB + 512);
            __syncthreads();

            f16x8 ah[2], bh[4];
#pragma unroll
            for (int mf = 0; mf < 2; ++mf)
                ah[mf] = *(const f16x8*)&oA[(wm + mf * 16 + lm) * 32 + quad * 8];
#pragma unroll
            for (int nf = 0; nf < 4; ++nf)
                bh[nf] = *(const f16x8*)&oB[(wn + nf * 16 + lm) * 32 + quad * 8];
#pragma unroll
            for (int mf = 0; mf < 2; ++mf)
#pragma unroll
                for (int nf = 0; nf < 4; ++nf)
                    acc[mf][nf] = __builtin_amdgcn_mfma_f32_16x16x32_f16(ah[mf], bh[nf], acc[mf][nf], 0, 0, 0);
        }

#pragma unroll
        for (int mf = 0; mf < 2; ++mf)
#pragma unroll
            for (int r = 0; r < 4; ++r) {
                const size_t m = (size_t)(mt * 64 + wm + mf * 16 + quad * 4 + r);
#pragma unroll
                for (int nf = 0; nf < 4; ++nf) {
                    const int col = nt * 128 + wn + nf * 16 + lm;
                    outp[m * Cc + col] = acc[mf][nf][r] + bo[col] + HS[m * Cc + col];
                }
            }
    }
}

// ---------------------------------------------------------------------------
extern "C" void kernel_launch(void* const* d_in, const int* in_sizes, int n_in,
                              void* d_out, int out_size, void* d_ws,
                              size_t ws_size, hipStream_t stream)
{
    const float* HS = (const float*)d_in[0];
    const float* Wq = (const float*)d_in[1];
    const float* Wk = (const float*)d_in[2];
    const float* Wv = (const float*)d_in[3];
    const float* Wo = (const float*)d_in[4];
    const float* bo = (const float*)d_in[5];
    float* out = (float*)d_out;

    const size_t SZ = (size_t)Bb * Tt * Cc;        // 4,194,304 elements
    _Float16* Qf  = (_Float16*)d_ws;
    _Float16* Kf  = Qf + SZ;
    _Float16* VTh = Kf + SZ;
    _Float16* HSh = VTh + SZ;
    _Float16* AO  = HSh + SZ;
    _Float16* Wt  = AO + SZ;                        // 4*Cc*Cc halves
    float* colsum = (float*)(Wt + 4 * Cc * Cc);

    int phase_all = -1;
    void* kargs[] = {
        (void*)&Wq, (void*)&Wk, (void*)&Wv, (void*)&Wo,
        (void*)&HS, (void*)&bo, (void*)&out,
        (void*)&Qf, (void*)&Kf, (void*)&VTh, (void*)&HSh,
        (void*)&AO, (void*)&Wt, (void*)&colsum, (void*)&phase_all
    };
    hipError_t err = hipLaunchCooperativeKernel(
        reinterpret_cast<void*>(mega), dim3(768), dim3(256), kargs, 0, stream);

    if (err != hipSuccess) {
        // Fallback: 4 regular dispatches, semantically identical (kernel
        // boundaries provide the inter-phase synchronization).
        for (int p = 0; p < 4; ++p)
            mega<<<dim3(768), dim3(256), 0, stream>>>(
                Wq, Wk, Wv, Wo, HS, bo, out,
                Qf, Kf, VTh, HSh, AO, Wt, colsum, p);
    }
}

// Round 13
// 228.602 us; speedup vs baseline: 3.5173x; 3.5173x over previous
//
#include <hip/hip_runtime.h>

#define Tt 2048
#define Cc 512
#define Bb 4
#define BC (Bb * Cc)

typedef __attribute__((ext_vector_type(4))) float f32x4;
typedef __attribute__((ext_vector_type(8))) _Float16 f16x8;
typedef __attribute__((ext_vector_type(4))) _Float16 f16x4;
typedef __attribute__((ext_vector_type(2))) _Float16 f16x2;

// async global->LDS 16B copy: dest = wave-uniform LDS base + lane*16.
__device__ static inline void gl16(const _Float16* g, _Float16* l)
{
    __builtin_amdgcn_global_load_lds(
        (const __attribute__((address_space(1))) void*)g,
        (__attribute__((address_space(3))) void*)l, 16, 0, 0);
}

// ---------------------------------------------------------------------------
// Kernel P: fused prep — blocks [0,2048): HS fp32->fp16; [2048,2304):
// W transpose->Wt fp16; [2304,2307): colsum zero.
// ---------------------------------------------------------------------------
__global__ __launch_bounds__(256) void prep(
    const float* __restrict__ Wq, const float* __restrict__ Wk,
    const float* __restrict__ Wv, const float* __restrict__ Wo,
    const float* __restrict__ HS, _Float16* __restrict__ Wt,
    _Float16* __restrict__ HSh, float* __restrict__ colsum)
{
    const int blk = blockIdx.x;
    const int tid = threadIdx.x;
    __shared__ float tile[64][65];

    if (blk < 2048) {
        const size_t i = ((size_t)blk * 256 + tid) * 8;
        float4 a = *(const float4*)&HS[i];
        float4 b = *(const float4*)&HS[i + 4];
        f16x8 o;
        o[0] = (_Float16)a.x; o[1] = (_Float16)a.y;
        o[2] = (_Float16)a.z; o[3] = (_Float16)a.w;
        o[4] = (_Float16)b.x; o[5] = (_Float16)b.y;
        o[6] = (_Float16)b.z; o[7] = (_Float16)b.w;
        *(f16x8*)&HSh[i] = o;
    } else if (blk < 2304) {
        const int lb = blk - 2048;
        const int z = lb >> 6, x = lb & 63;
        const float* W = (z == 0) ? Wq : (z == 1) ? Wk : (z == 2) ? Wv : Wo;
        const int k0 = (x >> 3) * 64, n0 = (x & 7) * 64;
#pragma unroll
        for (int i = 0; i < 4; ++i) {
            const int idx = i * 256 + tid;
            const int kr = idx >> 4, c4 = idx & 15;
            float4 v = *(const float4*)&W[(size_t)(k0 + kr) * Cc + n0 + c4 * 4];
            tile[kr][c4 * 4 + 0] = v.x; tile[kr][c4 * 4 + 1] = v.y;
            tile[kr][c4 * 4 + 2] = v.z; tile[kr][c4 * 4 + 3] = v.w;
        }
        __syncthreads();
#pragma unroll
        for (int i = 0; i < 4; ++i) {
            const int idx = i * 256 + tid;
            const int nr = idx >> 4, k4 = idx & 15;
            f16x4 o;
            o[0] = (_Float16)tile[k4 * 4 + 0][nr];
            o[1] = (_Float16)tile[k4 * 4 + 1][nr];
            o[2] = (_Float16)tile[k4 * 4 + 2][nr];
            o[3] = (_Float16)tile[k4 * 4 + 3][nr];
            *(f16x4*)&Wt[((size_t)(z * 512 + n0 + nr)) * Cc + k0 + k4 * 4] = o;
        }
    } else {
        const int i = (blk - 2304) * 2048 + tid * 8;
        *(f32x4*)&colsum[i]     = (f32x4){0.f, 0.f, 0.f, 0.f};
        *(f32x4*)&colsum[i + 4] = (f32x4){0.f, 0.f, 0.f, 0.f};
    }
}

// ---------------------------------------------------------------------------
// Kernel 1: QKV GEMM, fp16 MFMA, 128x128 tile, 4 waves, BK=32,
// global_load_lds staging. Epilogue: Q/K fp16 store; V (z==2) is written
// DIRECTLY as VT (transposed + kappa key-permutation) via an LDS bounce.
// All z accumulate per-(b,channel) sum-of-squares.
// ---------------------------------------------------------------------------
__global__ __launch_bounds__(256, 3) void qkv_mfma(
    const _Float16* __restrict__ HSh, const _Float16* __restrict__ Wt,
    _Float16* __restrict__ Qf, _Float16* __restrict__ Kf,
    _Float16* __restrict__ VTh, float* __restrict__ colsum)
{
    const int mt = blockIdx.x;              // 64
    const int nt = blockIdx.y;              // 4
    const int z  = blockIdx.z;              // 3

    const int tid = threadIdx.x;
    const int wave = tid >> 6, lane = tid & 63;
    const int quad = lane >> 4, lm = lane & 15;
    const int wm = (wave & 1) * 64, wn = (wave >> 1) * 64;

    __shared__ _Float16 smem[128 * 136];    // 34.8 KB
    _Float16* sA = smem;                    // 128*32
    _Float16* sB = smem + 128 * 32;         // 128*32

    f32x4 acc[4][4];
#pragma unroll
    for (int mf = 0; mf < 4; ++mf)
#pragma unroll
        for (int nf = 0; nf < 4; ++nf) acc[mf][nf] = (f32x4){0.f, 0.f, 0.f, 0.f};

    const int lr = lane >> 2;
    const int lc = (lane & 3) * 8;
    const _Float16* gaA = HSh + (size_t)(mt * 128 + wave * 32 + lr) * Cc + lc;
    const _Float16* gaB = Wt + ((size_t)(z * 512 + nt * 128 + wave * 32 + lr)) * Cc + lc;
    _Float16* ldA = &sA[wave * 1024];
    _Float16* ldB = &sB[wave * 1024];

    for (int k0 = 0; k0 < Cc; k0 += 32) {
        __syncthreads();
        gl16(gaA + k0,            ldA);
        gl16(gaA + 16 * Cc + k0,  ldA + 512);
        gl16(gaB + k0,            ldB);
        gl16(gaB + 16 * Cc + k0,  ldB + 512);
        __syncthreads();

        f16x8 ah[4], bh[4];
#pragma unroll
        for (int mf = 0; mf < 4; ++mf)
            ah[mf] = *(const f16x8*)&sA[(wm + mf * 16 + lm) * 32 + quad * 8];
#pragma unroll
        for (int nf = 0; nf < 4; ++nf)
            bh[nf] = *(const f16x8*)&sB[(wn + nf * 16 + lm) * 32 + quad * 8];
#pragma unroll
        for (int mf = 0; mf < 4; ++mf)
#pragma unroll
            for (int nf = 0; nf < 4; ++nf)
                acc[mf][nf] = __builtin_amdgcn_mfma_f32_16x16x32_f16(ah[mf], bh[nf], acc[mf][nf], 0, 0, 0);
    }

    const int bidx = mt >> 4;

    _Float16* Out = (z == 0) ? Qf : Kf;
#pragma unroll
    for (int nf = 0; nf < 4; ++nf) {
        float cs = 0.f;
#pragma unroll
        for (int mf = 0; mf < 4; ++mf)
#pragma unroll
            for (int r = 0; r < 4; ++r) {
                const float v = acc[mf][nf][r];
                cs += v * v;
                if (z < 2) {
                    const size_t idx =
                        (size_t)(mt * 128 + wm + mf * 16 + quad * 4 + r) * Cc +
                        nt * 128 + wn + nf * 16 + lm;
                    Out[idx] = (_Float16)v;
                }
            }
        cs += __shfl_xor(cs, 16, 64);
        cs += __shfl_xor(cs, 32, 64);
        if (lane < 16)
            atomicAdd(&colsum[(size_t)z * BC + bidx * Cc + nt * 128 + wn + nf * 16 + lane], cs);
    }

    if (z == 2) {
        __syncthreads();
#pragma unroll
        for (int nf = 0; nf < 4; ++nf) {
            const int c = wn + nf * 16 + lm;
#pragma unroll
            for (int mf = 0; mf < 4; ++mf) {
                const int m0 = wm + mf * 16 + quad * 4;
                const int tl = m0 & 63;
                const int u = tl >> 3, j0 = tl & 7;
                const int p0 = ((u >> 2) & 1) * 32 + (u & 1) * 16 +
                               ((u >> 1) & 1) * 4 + ((j0 >= 4) ? 8 : 0);
                const int tperm = (m0 & 64) + p0;
                f16x4 pk;
#pragma unroll
                for (int r = 0; r < 4; ++r) pk[r] = (_Float16)acc[mf][nf][r];
                *(f16x4*)&smem[c * 136 + tperm] = pk;
            }
        }
        __syncthreads();
        const int b = mt >> 4;
        const int tbase = (mt & 15) * 128;
#pragma unroll
        for (int i = 0; i < 8; ++i) {
            const int idx = i * 256 + tid;
            const int cr = idx >> 4, t8 = (idx & 15) * 8;
            f16x8 v = *(const f16x8*)&smem[cr * 136 + t8];
            *(f16x8*)&VTh[((size_t)(b * Cc) + nt * 128 + cr) * Tt + tbase + t8] = v;
        }
    }
}

// ---------------------------------------------------------------------------
// Kernel 4: fp16 MFMA flash attention, LDS-FREE. K/V panels are L2-resident
// (XCD-local grid, round-4 evidence: FETCH 12MB, HBM 5%), and all 4 waves
// read IDENTICAL fragments (L1 broadcast) -> staging through LDS was pure
// overhead (catalog m169). Fragments read direct global->reg each tile.
// Zero barriers, zero bank conflicts; waves free-run; QK(kt)|PV(kt-1)|exp(kt)
// pipeline kept; P in regs via pre-permuted VT; l via ones-MFMA; setprio;
// iq/ik/iv inline from colsum.
// ---------------------------------------------------------------------------
__global__ __launch_bounds__(256, 2) void attn_mfma(
    const _Float16* __restrict__ Qf, const _Float16* __restrict__ Kf,
    const _Float16* __restrict__ VT, const float* __restrict__ colsum,
    _Float16* __restrict__ AO)
{
    const int bid = blockIdx.x;           // 512
    const int qt = bid >> 5;              // 16
    const int bh = bid & 31;              // 32 (bid%8 == bh%8 -> XCD locality)
    const int b = bh >> 3, h = bh & 7;
    const int tid = threadIdx.x;
    const int wave = tid >> 6, lane = tid & 63;
    const int quad = lane >> 4, lm = lane & 15;
    const float invT = 1.0f / Tt;

    // ---- per-channel scale iq*ik*0.125*log2(e), from colsum inline
    float ss[2][8];
    {
        const float* csq = colsum + b * Cc + h * 64;
        const float* csk = colsum + BC + b * Cc + h * 64;
#pragma unroll
        for (int ks = 0; ks < 2; ++ks) {
            const int d0 = ks * 32 + quad * 8;
#pragma unroll
            for (int j = 0; j < 8; ++j) {
                const float iq = rsqrtf(csq[d0 + j] * invT + 1e-4f);
                const float ik = rsqrtf(csk[d0 + j] * invT + 1e-4f);
                ss[ks][j] = iq * ik * 0.18033688011f;
            }
        }
    }

    // ---- Q fragments (B-operand: n=lm=query, k=quad*8+j)
    f16x8 qb[2][2];
    {
#pragma unroll
        for (int qf = 0; qf < 2; ++qf) {
            const int row = qt * 128 + wave * 32 + qf * 16 + lm;
#pragma unroll
            for (int ks = 0; ks < 2; ++ks) {
                const int d0 = ks * 32 + quad * 8;
                f16x8 qv = *(const f16x8*)&Qf[(size_t)(b * Tt + row) * Cc + h * 64 + d0];
#pragma unroll
                for (int j = 0; j < 8; ++j)
                    qb[qf][ks][j] = (_Float16)((float)qv[j] * ss[ks][j]);
            }
        }
    }

    f32x4 o[4][2];
#pragma unroll
    for (int cf = 0; cf < 4; ++cf)
#pragma unroll
        for (int qf = 0; qf < 2; ++qf) o[cf][qf] = (f32x4){0.f, 0.f, 0.f, 0.f};
    f32x4 ol[2];
#pragma unroll
    for (int qf = 0; qf < 2; ++qf) ol[qf] = (f32x4){0.f, 0.f, 0.f, 0.f};
    f16x8 ones;
#pragma unroll
    for (int j = 0; j < 8; ++j) ones[j] = (_Float16)1.0f;

    f16x8 pb[2][2];
#pragma unroll
    for (int qf = 0; qf < 2; ++qf)
#pragma unroll
        for (int ks = 0; ks < 2; ++ks)
#pragma unroll
            for (int j = 0; j < 8; ++j) pb[qf][ks][j] = (_Float16)0.0f;

    const _Float16* gK = Kf + (size_t)b * Tt * Cc + h * 64;
    const _Float16* gV = VT + ((size_t)b * Cc + h * 64) * Tt;

    for (int kt = 0; kt < 32; ++kt) {
        // ---- K fragments of tile kt: direct global->reg (L1/L2 hit)
        f16x8 ka[2][4];
#pragma unroll
        for (int ks = 0; ks < 2; ++ks)
#pragma unroll
            for (int kf = 0; kf < 4; ++kf)
                ka[ks][kf] = *(const f16x8*)&gK[(size_t)(kt * 64 + kf * 16 + lm) * Cc + ks * 32 + quad * 8];

        // ---- S^T(kt) = K Q^T
        f32x4 st[4][2];
#pragma unroll
        for (int kf = 0; kf < 4; ++kf)
#pragma unroll
            for (int qf = 0; qf < 2; ++qf) st[kf][qf] = (f32x4){0.f, 0.f, 0.f, 0.f};
        __builtin_amdgcn_s_setprio(1);
#pragma unroll
        for (int ks = 0; ks < 2; ++ks)
#pragma unroll
            for (int kf = 0; kf < 4; ++kf)
#pragma unroll
                for (int qf = 0; qf < 2; ++qf)
                    st[kf][qf] = __builtin_amdgcn_mfma_f32_16x16x32_f16(ka[ks][kf], qb[qf][ks], st[kf][qf], 0, 0, 0);
        __builtin_amdgcn_s_setprio(0);

        // ---- PV(kt-1): V fragments direct global->reg
        if (kt > 0) {
            const int tp = (kt - 1) * 64;
#pragma unroll
            for (int ks = 0; ks < 2; ++ks) {
                f16x8 va[4];
#pragma unroll
                for (int cf = 0; cf < 4; ++cf)
                    va[cf] = *(const f16x8*)&gV[(size_t)(cf * 16 + lm) * Tt + tp + ks * 32 + quad * 8];
                __builtin_amdgcn_s_setprio(1);
#pragma unroll
                for (int cf = 0; cf < 4; ++cf)
#pragma unroll
                    for (int qf = 0; qf < 2; ++qf)
                        o[cf][qf] = __builtin_amdgcn_mfma_f32_16x16x32_f16(va[cf], pb[qf][ks], o[cf][qf], 0, 0, 0);
#pragma unroll
                for (int qf = 0; qf < 2; ++qf)
                    ol[qf] = __builtin_amdgcn_mfma_f32_16x16x32_f16(ones, pb[qf][ks], ol[qf], 0, 0, 0);
                __builtin_amdgcn_s_setprio(0);
            }
        }

        // ---- p = exp2(s(kt)) -> pb regs
#pragma unroll
        for (int ks = 0; ks < 2; ++ks)
#pragma unroll
            for (int qf = 0; qf < 2; ++qf) {
                const f32x4 a = st[2 * ks][qf];
                const f32x4 c = st[2 * ks + 1][qf];
                const f16x2 l0 = __builtin_bit_cast(f16x2, __builtin_amdgcn_cvt_pkrtz(
                    __builtin_amdgcn_exp2f(a[0]), __builtin_amdgcn_exp2f(a[1])));
                const f16x2 l1 = __builtin_bit_cast(f16x2, __builtin_amdgcn_cvt_pkrtz(
                    __builtin_amdgcn_exp2f(a[2]), __builtin_amdgcn_exp2f(a[3])));
                const f16x2 h0 = __builtin_bit_cast(f16x2, __builtin_amdgcn_cvt_pkrtz(
                    __builtin_amdgcn_exp2f(c[0]), __builtin_amdgcn_exp2f(c[1])));
                const f16x2 h1 = __builtin_bit_cast(f16x2, __builtin_amdgcn_cvt_pkrtz(
                    __builtin_amdgcn_exp2f(c[2]), __builtin_amdgcn_exp2f(c[3])));
                f16x8 p;
                p[0] = l0[0]; p[1] = l0[1]; p[2] = l1[0]; p[3] = l1[1];
                p[4] = h0[0]; p[5] = h0[1]; p[6] = h1[0]; p[7] = h1[1];
                pb[qf][ks] = p;
            }
    }

    // ---- drain PV(31)
    {
        const int tp = 31 * 64;
#pragma unroll
        for (int ks = 0; ks < 2; ++ks) {
            f16x8 va[4];
#pragma unroll
            for (int cf = 0; cf < 4; ++cf)
                va[cf] = *(const f16x8*)&gV[(size_t)(cf * 16 + lm) * Tt + tp + ks * 32 + quad * 8];
#pragma unroll
            for (int cf = 0; cf < 4; ++cf)
#pragma unroll
                for (int qf = 0; qf < 2; ++qf)
                    o[cf][qf] = __builtin_amdgcn_mfma_f32_16x16x32_f16(va[cf], pb[qf][ks], o[cf][qf], 0, 0, 0);
#pragma unroll
            for (int qf = 0; qf < 2; ++qf)
                ol[qf] = __builtin_amdgcn_mfma_f32_16x16x32_f16(ones, pb[qf][ks], ol[qf], 0, 0, 0);
        }
    }

    // ---- epilogue: il from ones-MFMA, iv inline from colsum
    float il[2];
#pragma unroll
    for (int qf = 0; qf < 2; ++qf) il[qf] = 1.0f / ol[qf][0];
    const float* csv = colsum + 2 * BC + b * Cc + h * 64;
    float iv[4][4];
#pragma unroll
    for (int cf = 0; cf < 4; ++cf) {
        float4 t = *(const float4*)&csv[cf * 16 + quad * 4];
        iv[cf][0] = rsqrtf(t.x * invT + 1e-4f);
        iv[cf][1] = rsqrtf(t.y * invT + 1e-4f);
        iv[cf][2] = rsqrtf(t.z * invT + 1e-4f);
        iv[cf][3] = rsqrtf(t.w * invT + 1e-4f);
    }
#pragma unroll
    for (int qf = 0; qf < 2; ++qf) {
        const size_t row = (size_t)(b * Tt + qt * 128 + wave * 32 + qf * 16 + lm);
#pragma unroll
        for (int cf = 0; cf < 4; ++cf) {
            f16x4 pk;
#pragma unroll
            for (int r = 0; r < 4; ++r)
                pk[r] = (_Float16)(o[cf][qf][r] * il[qf] * iv[cf][r]);
            *(f16x4*)&AO[row * Cc + h * 64 + cf * 16 + quad * 4] = pk;
        }
    }
}

// ---------------------------------------------------------------------------
// Kernel 5: out = AO @ Wo + bo + residual. 64x128 tile, 4 waves, BK=32,
// global_load_lds staging.
// ---------------------------------------------------------------------------
__global__ __launch_bounds__(256, 2) void out_mfma(
    const _Float16* __restrict__ AO, const _Float16* __restrict__ Wt,
    const float* __restrict__ bo, const float* __restrict__ HS,
    float* __restrict__ Outp)
{
    const int mt = blockIdx.x;              // 128
    const int nt = blockIdx.y;              // 4
    const int tid = threadIdx.x;
    const int wave = tid >> 6, lane = tid & 63;
    const int quad = lane >> 4, lm = lane & 15;
    const int wm = (wave & 1) * 32, wn = (wave >> 1) * 64;

    __shared__ _Float16 sA[64 * 32];
    __shared__ _Float16 sB[128 * 32];

    f32x4 acc[2][4];
#pragma unroll
    for (int mf = 0; mf < 2; ++mf)
#pragma unroll
        for (int nf = 0; nf < 4; ++nf) acc[mf][nf] = (f32x4){0.f, 0.f, 0.f, 0.f};

    const int lr = lane >> 2;
    const int lc = (lane & 3) * 8;
    const _Float16* gaA = AO + (size_t)(mt * 64 + wave * 16 + lr) * Cc + lc;
    const _Float16* gaB = Wt + ((size_t)(3 * 512 + nt * 128 + wave * 32 + lr)) * Cc + lc;
    _Float16* ldA = &sA[wave * 512];
    _Float16* ldB = &sB[wave * 1024];

    for (int k0 = 0; k0 < Cc; k0 += 32) {
        __syncthreads();
        gl16(gaA + k0,           ldA);
        gl16(gaB + k0,           ldB);
        gl16(gaB + 16 * Cc + k0, ldB + 512);
        __syncthreads();

        f16x8 ah[2], bh[4];
#pragma unroll
        for (int mf = 0; mf < 2; ++mf)
            ah[mf] = *(const f16x8*)&sA[(wm + mf * 16 + lm) * 32 + quad * 8];
#pragma unroll
        for (int nf = 0; nf < 4; ++nf)
            bh[nf] = *(const f16x8*)&sB[(wn + nf * 16 + lm) * 32 + quad * 8];
#pragma unroll
        for (int mf = 0; mf < 2; ++mf)
#pragma unroll
            for (int nf = 0; nf < 4; ++nf)
                acc[mf][nf] = __builtin_amdgcn_mfma_f32_16x16x32_f16(ah[mf], bh[nf], acc[mf][nf], 0, 0, 0);
    }

#pragma unroll
    for (int mf = 0; mf < 2; ++mf)
#pragma unroll
        for (int r = 0; r < 4; ++r) {
            const size_t m = (size_t)(mt * 64 + wm + mf * 16 + quad * 4 + r);
#pragma unroll
            for (int nf = 0; nf < 4; ++nf) {
                const int col = nt * 128 + wn + nf * 16 + lm;
                Outp[m * Cc + col] = acc[mf][nf][r] + bo[col] + HS[m * Cc + col];
            }
        }
}

// ---------------------------------------------------------------------------
extern "C" void kernel_launch(void* const* d_in, const int* in_sizes, int n_in,
                              void* d_out, int out_size, void* d_ws,
                              size_t ws_size, hipStream_t stream)
{
    const float* HS = (const float*)d_in[0];
    const float* Wq = (const float*)d_in[1];
    const float* Wk = (const float*)d_in[2];
    const float* Wv = (const float*)d_in[3];
    const float* Wo = (const float*)d_in[4];
    const float* bo = (const float*)d_in[5];
    float* out = (float*)d_out;

    const size_t SZ = (size_t)Bb * Tt * Cc;        // 4,194,304 elements
    _Float16* Qf  = (_Float16*)d_ws;
    _Float16* Kf  = Qf + SZ;
    _Float16* VTh = Kf + SZ;
    _Float16* HSh = VTh + SZ;
    _Float16* AO  = HSh + SZ;
    _Float16* Wt  = AO + SZ;                        // 4*Cc*Cc halves
    float* colsum = (float*)(Wt + 4 * Cc * Cc);

    prep<<<2307, 256, 0, stream>>>(Wq, Wk, Wv, Wo, HS, Wt, HSh, colsum);

    qkv_mfma<<<dim3(64, 4, 3), 256, 0, stream>>>(HSh, Wt, Qf, Kf, VTh, colsum);

    attn_mfma<<<dim3(512), 256, 0, stream>>>(Qf, Kf, VTh, colsum, AO);

    out_mfma<<<dim3(128, 4), 256, 0, stream>>>(AO, Wt, bo, HS, out);
}

// Round 14
// 186.035 us; speedup vs baseline: 4.3221x; 1.2288x over previous
//
#include <hip/hip_runtime.h>

#define Tt 2048
#define Cc 512
#define Bb 4
#define BC (Bb * Cc)

typedef __attribute__((ext_vector_type(4))) float f32x4;
typedef __attribute__((ext_vector_type(8))) _Float16 f16x8;
typedef __attribute__((ext_vector_type(4))) _Float16 f16x4;
typedef __attribute__((ext_vector_type(2))) _Float16 f16x2;

// async global->LDS 16B copy: dest = wave-uniform LDS base + lane*16.
__device__ static inline void gl16(const _Float16* g, _Float16* l)
{
    __builtin_amdgcn_global_load_lds(
        (const __attribute__((address_space(1))) void*)g,
        (__attribute__((address_space(3))) void*)l, 16, 0, 0);
}

// ---------------------------------------------------------------------------
// Kernel P: fused prep — blocks [0,2048): HS fp32->fp16; [2048,2304):
// W transpose->Wt fp16; [2304,2307): colsum zero.
// ---------------------------------------------------------------------------
__global__ __launch_bounds__(256) void prep(
    const float* __restrict__ Wq, const float* __restrict__ Wk,
    const float* __restrict__ Wv, const float* __restrict__ Wo,
    const float* __restrict__ HS, _Float16* __restrict__ Wt,
    _Float16* __restrict__ HSh, float* __restrict__ colsum)
{
    const int blk = blockIdx.x;
    const int tid = threadIdx.x;
    __shared__ float tile[64][65];

    if (blk < 2048) {
        const size_t i = ((size_t)blk * 256 + tid) * 8;
        float4 a = *(const float4*)&HS[i];
        float4 b = *(const float4*)&HS[i + 4];
        f16x8 o;
        o[0] = (_Float16)a.x; o[1] = (_Float16)a.y;
        o[2] = (_Float16)a.z; o[3] = (_Float16)a.w;
        o[4] = (_Float16)b.x; o[5] = (_Float16)b.y;
        o[6] = (_Float16)b.z; o[7] = (_Float16)b.w;
        *(f16x8*)&HSh[i] = o;
    } else if (blk < 2304) {
        const int lb = blk - 2048;
        const int z = lb >> 6, x = lb & 63;
        const float* W = (z == 0) ? Wq : (z == 1) ? Wk : (z == 2) ? Wv : Wo;
        const int k0 = (x >> 3) * 64, n0 = (x & 7) * 64;
#pragma unroll
        for (int i = 0; i < 4; ++i) {
            const int idx = i * 256 + tid;
            const int kr = idx >> 4, c4 = idx & 15;
            float4 v = *(const float4*)&W[(size_t)(k0 + kr) * Cc + n0 + c4 * 4];
            tile[kr][c4 * 4 + 0] = v.x; tile[kr][c4 * 4 + 1] = v.y;
            tile[kr][c4 * 4 + 2] = v.z; tile[kr][c4 * 4 + 3] = v.w;
        }
        __syncthreads();
#pragma unroll
        for (int i = 0; i < 4; ++i) {
            const int idx = i * 256 + tid;
            const int nr = idx >> 4, k4 = idx & 15;
            f16x4 o;
            o[0] = (_Float16)tile[k4 * 4 + 0][nr];
            o[1] = (_Float16)tile[k4 * 4 + 1][nr];
            o[2] = (_Float16)tile[k4 * 4 + 2][nr];
            o[3] = (_Float16)tile[k4 * 4 + 3][nr];
            *(f16x4*)&Wt[((size_t)(z * 512 + n0 + nr)) * Cc + k0 + k4 * 4] = o;
        }
    } else {
        const int i = (blk - 2304) * 2048 + tid * 8;
        *(f32x4*)&colsum[i]     = (f32x4){0.f, 0.f, 0.f, 0.f};
        *(f32x4*)&colsum[i + 4] = (f32x4){0.f, 0.f, 0.f, 0.f};
    }
}

// ---------------------------------------------------------------------------
// Kernel 1: QKV GEMM, fp16 MFMA, 128x128 tile, 4 waves, BK=32,
// global_load_lds staging. Epilogue: Q/K fp16 store; V (z==2) is written
// DIRECTLY as VT (transposed + kappa key-permutation) via an LDS bounce.
// All z accumulate per-(b,channel) sum-of-squares.
// ---------------------------------------------------------------------------
__global__ __launch_bounds__(256, 3) void qkv_mfma(
    const _Float16* __restrict__ HSh, const _Float16* __restrict__ Wt,
    _Float16* __restrict__ Qf, _Float16* __restrict__ Kf,
    _Float16* __restrict__ VTh, float* __restrict__ colsum)
{
    const int mt = blockIdx.x;              // 64
    const int nt = blockIdx.y;              // 4
    const int z  = blockIdx.z;              // 3

    const int tid = threadIdx.x;
    const int wave = tid >> 6, lane = tid & 63;
    const int quad = lane >> 4, lm = lane & 15;
    const int wm = (wave & 1) * 64, wn = (wave >> 1) * 64;

    __shared__ _Float16 smem[128 * 136];    // 34.8 KB
    _Float16* sA = smem;                    // 128*32
    _Float16* sB = smem + 128 * 32;         // 128*32

    f32x4 acc[4][4];
#pragma unroll
    for (int mf = 0; mf < 4; ++mf)
#pragma unroll
        for (int nf = 0; nf < 4; ++nf) acc[mf][nf] = (f32x4){0.f, 0.f, 0.f, 0.f};

    const int lr = lane >> 2;
    const int lc = (lane & 3) * 8;
    const _Float16* gaA = HSh + (size_t)(mt * 128 + wave * 32 + lr) * Cc + lc;
    const _Float16* gaB = Wt + ((size_t)(z * 512 + nt * 128 + wave * 32 + lr)) * Cc + lc;
    _Float16* ldA = &sA[wave * 1024];
    _Float16* ldB = &sB[wave * 1024];

    for (int k0 = 0; k0 < Cc; k0 += 32) {
        __syncthreads();
        gl16(gaA + k0,            ldA);
        gl16(gaA + 16 * Cc + k0,  ldA + 512);
        gl16(gaB + k0,            ldB);
        gl16(gaB + 16 * Cc + k0,  ldB + 512);
        __syncthreads();

        f16x8 ah[4], bh[4];
#pragma unroll
        for (int mf = 0; mf < 4; ++mf)
            ah[mf] = *(const f16x8*)&sA[(wm + mf * 16 + lm) * 32 + quad * 8];
#pragma unroll
        for (int nf = 0; nf < 4; ++nf)
            bh[nf] = *(const f16x8*)&sB[(wn + nf * 16 + lm) * 32 + quad * 8];
#pragma unroll
        for (int mf = 0; mf < 4; ++mf)
#pragma unroll
            for (int nf = 0; nf < 4; ++nf)
                acc[mf][nf] = __builtin_amdgcn_mfma_f32_16x16x32_f16(ah[mf], bh[nf], acc[mf][nf], 0, 0, 0);
    }

    const int bidx = mt >> 4;

    _Float16* Out = (z == 0) ? Qf : Kf;
#pragma unroll
    for (int nf = 0; nf < 4; ++nf) {
        float cs = 0.f;
#pragma unroll
        for (int mf = 0; mf < 4; ++mf)
#pragma unroll
            for (int r = 0; r < 4; ++r) {
                const float v = acc[mf][nf][r];
                cs += v * v;
                if (z < 2) {
                    const size_t idx =
                        (size_t)(mt * 128 + wm + mf * 16 + quad * 4 + r) * Cc +
                        nt * 128 + wn + nf * 16 + lm;
                    Out[idx] = (_Float16)v;
                }
            }
        cs += __shfl_xor(cs, 16, 64);
        cs += __shfl_xor(cs, 32, 64);
        if (lane < 16)
            atomicAdd(&colsum[(size_t)z * BC + bidx * Cc + nt * 128 + wn + nf * 16 + lane], cs);
    }

    if (z == 2) {
        __syncthreads();
#pragma unroll
        for (int nf = 0; nf < 4; ++nf) {
            const int c = wn + nf * 16 + lm;
#pragma unroll
            for (int mf = 0; mf < 4; ++mf) {
                const int m0 = wm + mf * 16 + quad * 4;
                const int tl = m0 & 63;
                const int u = tl >> 3, j0 = tl & 7;
                const int p0 = ((u >> 2) & 1) * 32 + (u & 1) * 16 +
                               ((u >> 1) & 1) * 4 + ((j0 >= 4) ? 8 : 0);
                const int tperm = (m0 & 64) + p0;
                f16x4 pk;
#pragma unroll
                for (int r = 0; r < 4; ++r) pk[r] = (_Float16)acc[mf][nf][r];
                *(f16x4*)&smem[c * 136 + tperm] = pk;
            }
        }
        __syncthreads();
        const int b = mt >> 4;
        const int tbase = (mt & 15) * 128;
#pragma unroll
        for (int i = 0; i < 8; ++i) {
            const int idx = i * 256 + tid;
            const int cr = idx >> 4, t8 = (idx & 15) * 8;
            f16x8 v = *(const f16x8*)&smem[cr * 136 + t8];
            *(f16x8*)&VTh[((size_t)(b * Cc) + nt * 128 + cr) * Tt + tbase + t8] = v;
        }
    }
}

// ---------------------------------------------------------------------------
// Kernel 4: fp16 MFMA flash attention, HYBRID staging.
// K: LDS double-buffered with one-tile-ahead register prefetch (round-11's
// working latency pipeline — K is consumed immediately after staging).
// V: direct global->reg (L1/L2-resident via XCD-local grid; V(kt-1) loads
// are issued right after the staging barrier, BEFORE the K-prefetch loads,
// so their latency hides under the QK MFMA phase and PV's vmcnt wait leaves
// the K prefetch in flight). Halves LDS traffic + bank conflicts vs full
// staging; avoids round-13's unhidden-latency stall.
// P in regs via pre-permuted VT; l via ones-MFMA; setprio; iq/ik/iv inline.
// ---------------------------------------------------------------------------
#define LSTR 72

__global__ __launch_bounds__(256, 3) void attn_mfma(
    const _Float16* __restrict__ Qf, const _Float16* __restrict__ Kf,
    const _Float16* __restrict__ VT, const float* __restrict__ colsum,
    _Float16* __restrict__ AO)
{
    const int bid = blockIdx.x;           // 512
    const int qt = bid >> 5;              // 16
    const int bh = bid & 31;              // 32 (bid%8 == bh%8 -> XCD locality)
    const int b = bh >> 3, h = bh & 7;
    const int tid = threadIdx.x;
    const int wave = tid >> 6, lane = tid & 63;
    const int quad = lane >> 4, lm = lane & 15;
    const float invT = 1.0f / Tt;

    __shared__ _Float16 sK[2][64 * LSTR];   // 18.4 KB (K only)

    // ---- per-channel scale iq*ik*0.125*log2(e), from colsum inline
    float ss[2][8];
    {
        const float* csq = colsum + b * Cc + h * 64;
        const float* csk = colsum + BC + b * Cc + h * 64;
#pragma unroll
        for (int ks = 0; ks < 2; ++ks) {
            const int d0 = ks * 32 + quad * 8;
#pragma unroll
            for (int j = 0; j < 8; ++j) {
                const float iq = rsqrtf(csq[d0 + j] * invT + 1e-4f);
                const float ik = rsqrtf(csk[d0 + j] * invT + 1e-4f);
                ss[ks][j] = iq * ik * 0.18033688011f;
            }
        }
    }

    // ---- Q fragments (B-operand: n=lm=query, k=quad*8+j)
    f16x8 qb[2][2];
    {
#pragma unroll
        for (int qf = 0; qf < 2; ++qf) {
            const int row = qt * 128 + wave * 32 + qf * 16 + lm;
#pragma unroll
            for (int ks = 0; ks < 2; ++ks) {
                const int d0 = ks * 32 + quad * 8;
                f16x8 qv = *(const f16x8*)&Qf[(size_t)(b * Tt + row) * Cc + h * 64 + d0];
#pragma unroll
                for (int j = 0; j < 8; ++j)
                    qb[qf][ks][j] = (_Float16)((float)qv[j] * ss[ks][j]);
            }
        }
    }

    f32x4 o[4][2];
#pragma unroll
    for (int cf = 0; cf < 4; ++cf)
#pragma unroll
        for (int qf = 0; qf < 2; ++qf) o[cf][qf] = (f32x4){0.f, 0.f, 0.f, 0.f};
    f32x4 ol[2];
#pragma unroll
    for (int qf = 0; qf < 2; ++qf) ol[qf] = (f32x4){0.f, 0.f, 0.f, 0.f};
    f16x8 ones;
#pragma unroll
    for (int j = 0; j < 8; ++j) ones[j] = (_Float16)1.0f;

    f16x8 pb[2][2];
#pragma unroll
    for (int qf = 0; qf < 2; ++qf)
#pragma unroll
        for (int ks = 0; ks < 2; ++ks)
#pragma unroll
            for (int j = 0; j < 8; ++j) pb[qf][ks][j] = (_Float16)0.0f;

    const int sr0 = tid >> 3, sc0 = (tid & 7) * 8;
    const int sr1 = sr0 + 32;
    const _Float16* gK = Kf + (size_t)b * Tt * Cc + h * 64;
    const _Float16* gV = VT + ((size_t)b * Cc + h * 64) * Tt;

    f16x8 rk0, rk1;
    {
        rk0 = *(const f16x8*)&gK[(size_t)sr0 * Cc + sc0];
        rk1 = *(const f16x8*)&gK[(size_t)sr1 * Cc + sc0];
    }

    for (int kt = 0; kt < 32; ++kt) {
        const int cur = kt & 1;
        _Float16* sKc = sK[cur];

        __syncthreads();
        *(f16x8*)&sKc[sr0 * LSTR + sc0] = rk0;
        *(f16x8*)&sKc[sr1 * LSTR + sc0] = rk1;
        __syncthreads();

        // ---- V(kt-1) fragment loads: issued FIRST (oldest in vmcnt queue)
        // so PV's wait drains only these, leaving K prefetch in flight.
        f16x8 va[2][4];
        if (kt > 0) {
            const int tp = (kt - 1) * 64;
#pragma unroll
            for (int ks = 0; ks < 2; ++ks)
#pragma unroll
                for (int cf = 0; cf < 4; ++cf)
                    va[ks][cf] = *(const f16x8*)&gV[(size_t)(cf * 16 + lm) * Tt + tp + ks * 32 + quad * 8];
        }

        // ---- K prefetch for kt+1 (latency hidden across whole iteration)
        if (kt < 31) {
            const int t0 = (kt + 1) * 64;
            rk0 = *(const f16x8*)&gK[(size_t)(t0 + sr0) * Cc + sc0];
            rk1 = *(const f16x8*)&gK[(size_t)(t0 + sr1) * Cc + sc0];
        }

        // ---- S^T(kt) = K Q^T   (K from LDS; V loads in flight underneath)
        f32x4 st[4][2];
#pragma unroll
        for (int kf = 0; kf < 4; ++kf)
#pragma unroll
            for (int qf = 0; qf < 2; ++qf) st[kf][qf] = (f32x4){0.f, 0.f, 0.f, 0.f};
#pragma unroll
        for (int ks = 0; ks < 2; ++ks) {
            f16x8 ka[4];
#pragma unroll
            for (int kf = 0; kf < 4; ++kf)
                ka[kf] = *(const f16x8*)&sKc[(kf * 16 + lm) * LSTR + ks * 32 + quad * 8];
            __builtin_amdgcn_s_setprio(1);
#pragma unroll
            for (int kf = 0; kf < 4; ++kf)
#pragma unroll
                for (int qf = 0; qf < 2; ++qf)
                    st[kf][qf] = __builtin_amdgcn_mfma_f32_16x16x32_f16(ka[kf], qb[qf][ks], st[kf][qf], 0, 0, 0);
            __builtin_amdgcn_s_setprio(0);
        }

        // ---- PV(kt-1): O^T += VT P^T ; l += ones P^T  (va now arrived)
        if (kt > 0) {
#pragma unroll
            for (int ks = 0; ks < 2; ++ks) {
                __builtin_amdgcn_s_setprio(1);
#pragma unroll
                for (int cf = 0; cf < 4; ++cf)
#pragma unroll
                    for (int qf = 0; qf < 2; ++qf)
                        o[cf][qf] = __builtin_amdgcn_mfma_f32_16x16x32_f16(va[ks][cf], pb[qf][ks], o[cf][qf], 0, 0, 0);
#pragma unroll
                for (int qf = 0; qf < 2; ++qf)
                    ol[qf] = __builtin_amdgcn_mfma_f32_16x16x32_f16(ones, pb[qf][ks], ol[qf], 0, 0, 0);
                __builtin_amdgcn_s_setprio(0);
            }
        }

        // ---- p = exp2(s(kt)) -> pb regs
#pragma unroll
        for (int ks = 0; ks < 2; ++ks)
#pragma unroll
            for (int qf = 0; qf < 2; ++qf) {
                const f32x4 a = st[2 * ks][qf];
                const f32x4 c = st[2 * ks + 1][qf];
                const f16x2 l0 = __builtin_bit_cast(f16x2, __builtin_amdgcn_cvt_pkrtz(
                    __builtin_amdgcn_exp2f(a[0]), __builtin_amdgcn_exp2f(a[1])));
                const f16x2 l1 = __builtin_bit_cast(f16x2, __builtin_amdgcn_cvt_pkrtz(
                    __builtin_amdgcn_exp2f(a[2]), __builtin_amdgcn_exp2f(a[3])));
                const f16x2 h0 = __builtin_bit_cast(f16x2, __builtin_amdgcn_cvt_pkrtz(
                    __builtin_amdgcn_exp2f(c[0]), __builtin_amdgcn_exp2f(c[1])));
                const f16x2 h1 = __builtin_bit_cast(f16x2, __builtin_amdgcn_cvt_pkrtz(
                    __builtin_amdgcn_exp2f(c[2]), __builtin_amdgcn_exp2f(c[3])));
                f16x8 p;
                p[0] = l0[0]; p[1] = l0[1]; p[2] = l1[0]; p[3] = l1[1];
                p[4] = h0[0]; p[5] = h0[1]; p[6] = h1[0]; p[7] = h1[1];
                pb[qf][ks] = p;
            }
    }

    // ---- drain PV(31): direct V loads
    {
        const int tp = 31 * 64;
#pragma unroll
        for (int ks = 0; ks < 2; ++ks) {
            f16x8 va[4];
#pragma unroll
            for (int cf = 0; cf < 4; ++cf)
                va[cf] = *(const f16x8*)&gV[(size_t)(cf * 16 + lm) * Tt + tp + ks * 32 + quad * 8];
#pragma unroll
            for (int cf = 0; cf < 4; ++cf)
#pragma unroll
                for (int qf = 0; qf < 2; ++qf)
                    o[cf][qf] = __builtin_amdgcn_mfma_f32_16x16x32_f16(va[cf], pb[qf][ks], o[cf][qf], 0, 0, 0);
#pragma unroll
            for (int qf = 0; qf < 2; ++qf)
                ol[qf] = __builtin_amdgcn_mfma_f32_16x16x32_f16(ones, pb[qf][ks], ol[qf], 0, 0, 0);
        }
    }

    // ---- epilogue: il from ones-MFMA, iv inline from colsum
    float il[2];
#pragma unroll
    for (int qf = 0; qf < 2; ++qf) il[qf] = 1.0f / ol[qf][0];
    const float* csv = colsum + 2 * BC + b * Cc + h * 64;
    float iv[4][4];
#pragma unroll
    for (int cf = 0; cf < 4; ++cf) {
        float4 t = *(const float4*)&csv[cf * 16 + quad * 4];
        iv[cf][0] = rsqrtf(t.x * invT + 1e-4f);
        iv[cf][1] = rsqrtf(t.y * invT + 1e-4f);
        iv[cf][2] = rsqrtf(t.z * invT + 1e-4f);
        iv[cf][3] = rsqrtf(t.w * invT + 1e-4f);
    }
#pragma unroll
    for (int qf = 0; qf < 2; ++qf) {
        const size_t row = (size_t)(b * Tt + qt * 128 + wave * 32 + qf * 16 + lm);
#pragma unroll
        for (int cf = 0; cf < 4; ++cf) {
            f16x4 pk;
#pragma unroll
            for (int r = 0; r < 4; ++r)
                pk[r] = (_Float16)(o[cf][qf][r] * il[qf] * iv[cf][r]);
            *(f16x4*)&AO[row * Cc + h * 64 + cf * 16 + quad * 4] = pk;
        }
    }
}

// ---------------------------------------------------------------------------
// Kernel 5: out = AO @ Wo + bo + residual. 64x128 tile, 4 waves, BK=32,
// global_load_lds staging.
// ---------------------------------------------------------------------------
__global__ __launch_bounds__(256, 2) void out_mfma(
    const _Float16* __restrict__ AO, const _Float16* __restrict__ Wt,
    const float* __restrict__ bo, const float* __restrict__ HS,
    float* __restrict__ Outp)
{
    const int mt = blockIdx.x;              // 128
    const int nt = blockIdx.y;              // 4
    const int tid = threadIdx.x;
    const int wave = tid >> 6, lane = tid & 63;
    const int quad = lane >> 4, lm = lane & 15;
    const int wm = (wave & 1) * 32, wn = (wave >> 1) * 64;

    __shared__ _Float16 sA[64 * 32];
    __shared__ _Float16 sB[128 * 32];

    f32x4 acc[2][4];
#pragma unroll
    for (int mf = 0; mf < 2; ++mf)
#pragma unroll
        for (int nf = 0; nf < 4; ++nf) acc[mf][nf] = (f32x4){0.f, 0.f, 0.f, 0.f};

    const int lr = lane >> 2;
    const int lc = (lane & 3) * 8;
    const _Float16* gaA = AO + (size_t)(mt * 64 + wave * 16 + lr) * Cc + lc;
    const _Float16* gaB = Wt + ((size_t)(3 * 512 + nt * 128 + wave * 32 + lr)) * Cc + lc;
    _Float16* ldA = &sA[wave * 512];
    _Float16* ldB = &sB[wave * 1024];

    for (int k0 = 0; k0 < Cc; k0 += 32) {
        __syncthreads();
        gl16(gaA + k0,           ldA);
        gl16(gaB + k0,           ldB);
        gl16(gaB + 16 * Cc + k0, ldB + 512);
        __syncthreads();

        f16x8 ah[2], bh[4];
#pragma unroll
        for (int mf = 0; mf < 2; ++mf)
            ah[mf] = *(const f16x8*)&sA[(wm + mf * 16 + lm) * 32 + quad * 8];
#pragma unroll
        for (int nf = 0; nf < 4; ++nf)
            bh[nf] = *(const f16x8*)&sB[(wn + nf * 16 + lm) * 32 + quad * 8];
#pragma unroll
        for (int mf = 0; mf < 2; ++mf)
#pragma unroll
            for (int nf = 0; nf < 4; ++nf)
                acc[mf][nf] = __builtin_amdgcn_mfma_f32_16x16x32_f16(ah[mf], bh[nf], acc[mf][nf], 0, 0, 0);
    }

#pragma unroll
    for (int mf = 0; mf < 2; ++mf)
#pragma unroll
        for (int r = 0; r < 4; ++r) {
            const size_t m = (size_t)(mt * 64 + wm + mf * 16 + quad * 4 + r);
#pragma unroll
            for (int nf = 0; nf < 4; ++nf) {
                const int col = nt * 128 + wn + nf * 16 + lm;
                Outp[m * Cc + col] = acc[mf][nf][r] + bo[col] + HS[m * Cc + col];
            }
        }
}

// ---------------------------------------------------------------------------
extern "C" void kernel_launch(void* const* d_in, const int* in_sizes, int n_in,
                              void* d_out, int out_size, void* d_ws,
                              size_t ws_size, hipStream_t stream)
{
    const float* HS = (const float*)d_in[0];
    const float* Wq = (const float*)d_in[1];
    const float* Wk = (const float*)d_in[2];
    const float* Wv = (const float*)d_in[3];
    const float* Wo = (const float*)d_in[4];
    const float* bo = (const float*)d_in[5];
    float* out = (float*)d_out;

    const size_t SZ = (size_t)Bb * Tt * Cc;        // 4,194,304 elements
    _Float16* Qf  = (_Float16*)d_ws;
    _Float16* Kf  = Qf + SZ;
    _Float16* VTh = Kf + SZ;
    _Float16* HSh = VTh + SZ;
    _Float16* AO  = HSh + SZ;
    _Float16* Wt  = AO + SZ;                        // 4*Cc*Cc halves
    float* colsum = (float*)(Wt + 4 * Cc * Cc);

    prep<<<2307, 256, 0, stream>>>(Wq, Wk, Wv, Wo, HS, Wt, HSh, colsum);

    qkv_mfma<<<dim3(64, 4, 3), 256, 0, stream>>>(HSh, Wt, Qf, Kf, VTh, colsum);

    attn_mfma<<<dim3(512), 256, 0, stream>>>(Qf, Kf, VTh, colsum, AO);

    out_mfma<<<dim3(128, 4), 256, 0, stream>>>(AO, Wt, bo, HS, out);
}

// Round 15
// 165.903 us; speedup vs baseline: 4.8465x; 1.1213x over previous
//
#include <hip/hip_runtime.h>

#define Tt 2048
#define Cc 512
#define Bb 4
#define BC (Bb * Cc)

typedef __attribute__((ext_vector_type(4))) float f32x4;
typedef __attribute__((ext_vector_type(8))) _Float16 f16x8;
typedef __attribute__((ext_vector_type(4))) _Float16 f16x4;
typedef __attribute__((ext_vector_type(2))) _Float16 f16x2;

// async global->LDS 16B copy: dest = wave-uniform LDS base + lane*16.
__device__ static inline void gl16(const _Float16* g, _Float16* l)
{
    __builtin_amdgcn_global_load_lds(
        (const __attribute__((address_space(1))) void*)g,
        (__attribute__((address_space(3))) void*)l, 16, 0, 0);
}

// ---------------------------------------------------------------------------
// Kernel P: fused prep — blocks [0,2048): HS fp32->fp16; [2048,2304):
// W transpose->Wt fp16; [2304,2307): colsum zero.
// ---------------------------------------------------------------------------
__global__ __launch_bounds__(256) void prep(
    const float* __restrict__ Wq, const float* __restrict__ Wk,
    const float* __restrict__ Wv, const float* __restrict__ Wo,
    const float* __restrict__ HS, _Float16* __restrict__ Wt,
    _Float16* __restrict__ HSh, float* __restrict__ colsum)
{
    const int blk = blockIdx.x;
    const int tid = threadIdx.x;
    __shared__ float tile[64][65];

    if (blk < 2048) {
        const size_t i = ((size_t)blk * 256 + tid) * 8;
        float4 a = *(const float4*)&HS[i];
        float4 b = *(const float4*)&HS[i + 4];
        f16x8 o;
        o[0] = (_Float16)a.x; o[1] = (_Float16)a.y;
        o[2] = (_Float16)a.z; o[3] = (_Float16)a.w;
        o[4] = (_Float16)b.x; o[5] = (_Float16)b.y;
        o[6] = (_Float16)b.z; o[7] = (_Float16)b.w;
        *(f16x8*)&HSh[i] = o;
    } else if (blk < 2304) {
        const int lb = blk - 2048;
        const int z = lb >> 6, x = lb & 63;
        const float* W = (z == 0) ? Wq : (z == 1) ? Wk : (z == 2) ? Wv : Wo;
        const int k0 = (x >> 3) * 64, n0 = (x & 7) * 64;
#pragma unroll
        for (int i = 0; i < 4; ++i) {
            const int idx = i * 256 + tid;
            const int kr = idx >> 4, c4 = idx & 15;
            float4 v = *(const float4*)&W[(size_t)(k0 + kr) * Cc + n0 + c4 * 4];
            tile[kr][c4 * 4 + 0] = v.x; tile[kr][c4 * 4 + 1] = v.y;
            tile[kr][c4 * 4 + 2] = v.z; tile[kr][c4 * 4 + 3] = v.w;
        }
        __syncthreads();
#pragma unroll
        for (int i = 0; i < 4; ++i) {
            const int idx = i * 256 + tid;
            const int nr = idx >> 4, k4 = idx & 15;
            f16x4 o;
            o[0] = (_Float16)tile[k4 * 4 + 0][nr];
            o[1] = (_Float16)tile[k4 * 4 + 1][nr];
            o[2] = (_Float16)tile[k4 * 4 + 2][nr];
            o[3] = (_Float16)tile[k4 * 4 + 3][nr];
            *(f16x4*)&Wt[((size_t)(z * 512 + n0 + nr)) * Cc + k0 + k4 * 4] = o;
        }
    } else {
        const int i = (blk - 2304) * 2048 + tid * 8;
        *(f32x4*)&colsum[i]     = (f32x4){0.f, 0.f, 0.f, 0.f};
        *(f32x4*)&colsum[i + 4] = (f32x4){0.f, 0.f, 0.f, 0.f};
    }
}

// ---------------------------------------------------------------------------
// Kernel 1: QKV GEMM, fp16 MFMA, 128x128 tile, 4 waves, BK=32,
// global_load_lds staging. Epilogue: Q/K fp16 store; V (z==2) is written
// DIRECTLY as VT (transposed + kappa key-permutation) via an LDS bounce.
// All z accumulate per-(b,channel) sum-of-squares.
// ---------------------------------------------------------------------------
__global__ __launch_bounds__(256, 3) void qkv_mfma(
    const _Float16* __restrict__ HSh, const _Float16* __restrict__ Wt,
    _Float16* __restrict__ Qf, _Float16* __restrict__ Kf,
    _Float16* __restrict__ VTh, float* __restrict__ colsum)
{
    const int mt = blockIdx.x;              // 64
    const int nt = blockIdx.y;              // 4
    const int z  = blockIdx.z;              // 3

    const int tid = threadIdx.x;
    const int wave = tid >> 6, lane = tid & 63;
    const int quad = lane >> 4, lm = lane & 15;
    const int wm = (wave & 1) * 64, wn = (wave >> 1) * 64;

    __shared__ _Float16 smem[128 * 136];    // 34.8 KB
    _Float16* sA = smem;                    // 128*32
    _Float16* sB = smem + 128 * 32;         // 128*32

    f32x4 acc[4][4];
#pragma unroll
    for (int mf = 0; mf < 4; ++mf)
#pragma unroll
        for (int nf = 0; nf < 4; ++nf) acc[mf][nf] = (f32x4){0.f, 0.f, 0.f, 0.f};

    const int lr = lane >> 2;
    const int lc = (lane & 3) * 8;
    const _Float16* gaA = HSh + (size_t)(mt * 128 + wave * 32 + lr) * Cc + lc;
    const _Float16* gaB = Wt + ((size_t)(z * 512 + nt * 128 + wave * 32 + lr)) * Cc + lc;
    _Float16* ldA = &sA[wave * 1024];
    _Float16* ldB = &sB[wave * 1024];

    for (int k0 = 0; k0 < Cc; k0 += 32) {
        __syncthreads();
        gl16(gaA + k0,            ldA);
        gl16(gaA + 16 * Cc + k0,  ldA + 512);
        gl16(gaB + k0,            ldB);
        gl16(gaB + 16 * Cc + k0,  ldB + 512);
        __syncthreads();

        f16x8 ah[4], bh[4];
#pragma unroll
        for (int mf = 0; mf < 4; ++mf)
            ah[mf] = *(const f16x8*)&sA[(wm + mf * 16 + lm) * 32 + quad * 8];
#pragma unroll
        for (int nf = 0; nf < 4; ++nf)
            bh[nf] = *(const f16x8*)&sB[(wn + nf * 16 + lm) * 32 + quad * 8];
#pragma unroll
        for (int mf = 0; mf < 4; ++mf)
#pragma unroll
            for (int nf = 0; nf < 4; ++nf)
                acc[mf][nf] = __builtin_amdgcn_mfma_f32_16x16x32_f16(ah[mf], bh[nf], acc[mf][nf], 0, 0, 0);
    }

    const int bidx = mt >> 4;

    _Float16* Out = (z == 0) ? Qf : Kf;
#pragma unroll
    for (int nf = 0; nf < 4; ++nf) {
        float cs = 0.f;
#pragma unroll
        for (int mf = 0; mf < 4; ++mf)
#pragma unroll
            for (int r = 0; r < 4; ++r) {
                const float v = acc[mf][nf][r];
                cs += v * v;
                if (z < 2) {
                    const size_t idx =
                        (size_t)(mt * 128 + wm + mf * 16 + quad * 4 + r) * Cc +
                        nt * 128 + wn + nf * 16 + lm;
                    Out[idx] = (_Float16)v;
                }
            }
        cs += __shfl_xor(cs, 16, 64);
        cs += __shfl_xor(cs, 32, 64);
        if (lane < 16)
            atomicAdd(&colsum[(size_t)z * BC + bidx * Cc + nt * 128 + wn + nf * 16 + lane], cs);
    }

    if (z == 2) {
        __syncthreads();
#pragma unroll
        for (int nf = 0; nf < 4; ++nf) {
            const int c = wn + nf * 16 + lm;
#pragma unroll
            for (int mf = 0; mf < 4; ++mf) {
                const int m0 = wm + mf * 16 + quad * 4;
                const int tl = m0 & 63;
                const int u = tl >> 3, j0 = tl & 7;
                const int p0 = ((u >> 2) & 1) * 32 + (u & 1) * 16 +
                               ((u >> 1) & 1) * 4 + ((j0 >= 4) ? 8 : 0);
                const int tperm = (m0 & 64) + p0;
                f16x4 pk;
#pragma unroll
                for (int r = 0; r < 4; ++r) pk[r] = (_Float16)acc[mf][nf][r];
                *(f16x4*)&smem[c * 136 + tperm] = pk;
            }
        }
        __syncthreads();
        const int b = mt >> 4;
        const int tbase = (mt & 15) * 128;
#pragma unroll
        for (int i = 0; i < 8; ++i) {
            const int idx = i * 256 + tid;
            const int cr = idx >> 4, t8 = (idx & 15) * 8;
            f16x8 v = *(const f16x8*)&smem[cr * 136 + t8];
            *(f16x8*)&VTh[((size_t)(b * Cc) + nt * 128 + cr) * Tt + tbase + t8] = v;
        }
    }
}

// ---------------------------------------------------------------------------
// Kernel 4: fp16 MFMA flash attention, round-11 compute structure with
// global_load_lds async staging (m97 pattern, proven in qkv):
// - K/V staged coalesced global -> linear [ks][64][32] LDS blocks (the exact
//   qkv staging/read layout), no VGPR round-trip, no ds_writes.
// - ONE barrier per iter: vmcnt(0)+s_barrier at loop top publishes tile kt
//   (loads issued a full iteration earlier -> latency hidden); tile kt+1's
//   loads issued right after.
// - V triple-buffered (PV lags one tile: staging kt+1 must not overwrite
//   V[kt-1]); K double-buffered. LDS 40KB -> 4 blocks/CU at (256,4).
// P in regs via pre-permuted VT; l via ones-MFMA; setprio; iq/ik/iv inline.
// ---------------------------------------------------------------------------
__global__ __launch_bounds__(256, 4) void attn_mfma(
    const _Float16* __restrict__ Qf, const _Float16* __restrict__ Kf,
    const _Float16* __restrict__ VT, const float* __restrict__ colsum,
    _Float16* __restrict__ AO)
{
    const int bid = blockIdx.x;           // 512
    const int qt = bid >> 5;              // 16
    const int bh = bid & 31;              // 32 (bid%8 == bh%8 -> XCD locality)
    const int b = bh >> 3, h = bh & 7;
    const int tid = threadIdx.x;
    const int wave = tid >> 6, lane = tid & 63;
    const int quad = lane >> 4, lm = lane & 15;
    const float invT = 1.0f / Tt;

    __shared__ _Float16 sK[2][2][64 * 32];   // [buf][ks][row*32], 16 KB
    __shared__ _Float16 sV[3][2][64 * 32];   // [buf][ks][row*32], 24 KB

    // ---- per-channel scale iq*ik*0.125*log2(e), from colsum inline
    float ss[2][8];
    {
        const float* csq = colsum + b * Cc + h * 64;
        const float* csk = colsum + BC + b * Cc + h * 64;
#pragma unroll
        for (int ks = 0; ks < 2; ++ks) {
            const int d0 = ks * 32 + quad * 8;
#pragma unroll
            for (int j = 0; j < 8; ++j) {
                const float iq = rsqrtf(csq[d0 + j] * invT + 1e-4f);
                const float ik = rsqrtf(csk[d0 + j] * invT + 1e-4f);
                ss[ks][j] = iq * ik * 0.18033688011f;
            }
        }
    }

    // ---- Q fragments (B-operand: n=lm=query, k=quad*8+j)
    f16x8 qb[2][2];
    {
#pragma unroll
        for (int qf = 0; qf < 2; ++qf) {
            const int row = qt * 128 + wave * 32 + qf * 16 + lm;
#pragma unroll
            for (int ks = 0; ks < 2; ++ks) {
                const int d0 = ks * 32 + quad * 8;
                f16x8 qv = *(const f16x8*)&Qf[(size_t)(b * Tt + row) * Cc + h * 64 + d0];
#pragma unroll
                for (int j = 0; j < 8; ++j)
                    qb[qf][ks][j] = (_Float16)((float)qv[j] * ss[ks][j]);
            }
        }
    }

    f32x4 o[4][2];
#pragma unroll
    for (int cf = 0; cf < 4; ++cf)
#pragma unroll
        for (int qf = 0; qf < 2; ++qf) o[cf][qf] = (f32x4){0.f, 0.f, 0.f, 0.f};
    f32x4 ol[2];
#pragma unroll
    for (int qf = 0; qf < 2; ++qf) ol[qf] = (f32x4){0.f, 0.f, 0.f, 0.f};
    f16x8 ones;
#pragma unroll
    for (int j = 0; j < 8; ++j) ones[j] = (_Float16)1.0f;

    f16x8 pb[2][2];
#pragma unroll
    for (int qf = 0; qf < 2; ++qf)
#pragma unroll
        for (int ks = 0; ks < 2; ++ks)
#pragma unroll
            for (int j = 0; j < 8; ++j) pb[qf][ks][j] = (_Float16)0.0f;

    // staging geometry: thread covers row = tid>>2 (key for K, channel for
    // V), 8-half chunk c = (tid&3)*8. gl16 dest = wave-uniform base +
    // lane*16B -> halves offset tid*8 == row*32 + c  (consistent).
    const int srow = tid >> 2, sc8 = (tid & 3) * 8;
    const _Float16* gK = Kf + (size_t)b * Tt * Cc + h * 64;
    const _Float16* gV = VT + ((size_t)b * Cc + h * 64) * Tt;

#define STAGE_TILE(t, kb, vb)                                                  \
    do {                                                                       \
        const int _t0 = (t) * 64;                                              \
        gl16(&gK[(size_t)(_t0 + srow) * Cc + sc8],      &sK[kb][0][wave * 512]); \
        gl16(&gK[(size_t)(_t0 + srow) * Cc + 32 + sc8], &sK[kb][1][wave * 512]); \
        gl16(&gV[(size_t)srow * Tt + _t0 + sc8],        &sV[vb][0][wave * 512]); \
        gl16(&gV[(size_t)srow * Tt + _t0 + 32 + sc8],   &sV[vb][1][wave * 512]); \
    } while (0)

    STAGE_TILE(0, 0, 0);

    for (int kt = 0; kt < 32; ++kt) {
        const int kcur = kt & 1;
        // __syncthreads() implies s_waitcnt vmcnt(0): publishes tile kt
        // (its gl16s were issued one full iteration ago -> latency hidden)
        // and guarantees reads of the buffers being overwritten are done.
        __syncthreads();

        if (kt < 31) {
            const int vb = (kt + 1) % 3;
            STAGE_TILE(kt + 1, kcur ^ 1, vb);
        }

        // ---- S^T(kt) = K Q^T  (K from sK[kcur])
        f32x4 st[4][2];
#pragma unroll
        for (int kf = 0; kf < 4; ++kf)
#pragma unroll
            for (int qf = 0; qf < 2; ++qf) st[kf][qf] = (f32x4){0.f, 0.f, 0.f, 0.f};
#pragma unroll
        for (int ks = 0; ks < 2; ++ks) {
            f16x8 ka[4];
#pragma unroll
            for (int kf = 0; kf < 4; ++kf)
                ka[kf] = *(const f16x8*)&sK[kcur][ks][(kf * 16 + lm) * 32 + quad * 8];
            __builtin_amdgcn_s_setprio(1);
#pragma unroll
            for (int kf = 0; kf < 4; ++kf)
#pragma unroll
                for (int qf = 0; qf < 2; ++qf)
                    st[kf][qf] = __builtin_amdgcn_mfma_f32_16x16x32_f16(ka[kf], qb[qf][ks], st[kf][qf], 0, 0, 0);
            __builtin_amdgcn_s_setprio(0);
        }

        // ---- PV(kt-1): O^T += VT P^T ; l += ones P^T  (V from sV[(kt-1)%3])
        if (kt > 0) {
            const int vprv = (kt - 1) % 3;
#pragma unroll
            for (int ks = 0; ks < 2; ++ks) {
                f16x8 va[4];
#pragma unroll
                for (int cf = 0; cf < 4; ++cf)
                    va[cf] = *(const f16x8*)&sV[vprv][ks][(cf * 16 + lm) * 32 + quad * 8];
                __builtin_amdgcn_s_setprio(1);
#pragma unroll
                for (int cf = 0; cf < 4; ++cf)
#pragma unroll
                    for (int qf = 0; qf < 2; ++qf)
                        o[cf][qf] = __builtin_amdgcn_mfma_f32_16x16x32_f16(va[cf], pb[qf][ks], o[cf][qf], 0, 0, 0);
#pragma unroll
                for (int qf = 0; qf < 2; ++qf)
                    ol[qf] = __builtin_amdgcn_mfma_f32_16x16x32_f16(ones, pb[qf][ks], ol[qf], 0, 0, 0);
                __builtin_amdgcn_s_setprio(0);
            }
        }

        // ---- p = exp2(s(kt)) -> pb regs
#pragma unroll
        for (int ks = 0; ks < 2; ++ks)
#pragma unroll
            for (int qf = 0; qf < 2; ++qf) {
                const f32x4 a = st[2 * ks][qf];
                const f32x4 c = st[2 * ks + 1][qf];
                const f16x2 l0 = __builtin_bit_cast(f16x2, __builtin_amdgcn_cvt_pkrtz(
                    __builtin_amdgcn_exp2f(a[0]), __builtin_amdgcn_exp2f(a[1])));
                const f16x2 l1 = __builtin_bit_cast(f16x2, __builtin_amdgcn_cvt_pkrtz(
                    __builtin_amdgcn_exp2f(a[2]), __builtin_amdgcn_exp2f(a[3])));
                const f16x2 h0 = __builtin_bit_cast(f16x2, __builtin_amdgcn_cvt_pkrtz(
                    __builtin_amdgcn_exp2f(c[0]), __builtin_amdgcn_exp2f(c[1])));
                const f16x2 h1 = __builtin_bit_cast(f16x2, __builtin_amdgcn_cvt_pkrtz(
                    __builtin_amdgcn_exp2f(c[2]), __builtin_amdgcn_exp2f(c[3])));
                f16x8 p;
                p[0] = l0[0]; p[1] = l0[1]; p[2] = l1[0]; p[3] = l1[1];
                p[4] = h0[0]; p[5] = h0[1]; p[6] = h1[0]; p[7] = h1[1];
                pb[qf][ks] = p;
            }
    }

    // ---- drain PV(31): V tile 31 lives in sV[31 % 3 == 1]
    {
#pragma unroll
        for (int ks = 0; ks < 2; ++ks) {
            f16x8 va[4];
#pragma unroll
            for (int cf = 0; cf < 4; ++cf)
                va[cf] = *(const f16x8*)&sV[1][ks][(cf * 16 + lm) * 32 + quad * 8];
#pragma unroll
            for (int cf = 0; cf < 4; ++cf)
#pragma unroll
                for (int qf = 0; qf < 2; ++qf)
                    o[cf][qf] = __builtin_amdgcn_mfma_f32_16x16x32_f16(va[cf], pb[qf][ks], o[cf][qf], 0, 0, 0);
#pragma unroll
            for (int qf = 0; qf < 2; ++qf)
                ol[qf] = __builtin_amdgcn_mfma_f32_16x16x32_f16(ones, pb[qf][ks], ol[qf], 0, 0, 0);
        }
    }

    // ---- epilogue: il from ones-MFMA, iv inline from colsum
    float il[2];
#pragma unroll
    for (int qf = 0; qf < 2; ++qf) il[qf] = 1.0f / ol[qf][0];
    const float* csv = colsum + 2 * BC + b * Cc + h * 64;
    float iv[4][4];
#pragma unroll
    for (int cf = 0; cf < 4; ++cf) {
        float4 t = *(const float4*)&csv[cf * 16 + quad * 4];
        iv[cf][0] = rsqrtf(t.x * invT + 1e-4f);
        iv[cf][1] = rsqrtf(t.y * invT + 1e-4f);
        iv[cf][2] = rsqrtf(t.z * invT + 1e-4f);
        iv[cf][3] = rsqrtf(t.w * invT + 1e-4f);
    }
#pragma unroll
    for (int qf = 0; qf < 2; ++qf) {
        const size_t row = (size_t)(b * Tt + qt * 128 + wave * 32 + qf * 16 + lm);
#pragma unroll
        for (int cf = 0; cf < 4; ++cf) {
            f16x4 pk;
#pragma unroll
            for (int r = 0; r < 4; ++r)
                pk[r] = (_Float16)(o[cf][qf][r] * il[qf] * iv[cf][r]);
            *(f16x4*)&AO[row * Cc + h * 64 + cf * 16 + quad * 4] = pk;
        }
    }
#undef STAGE_TILE
}

// ---------------------------------------------------------------------------
// Kernel 5: out = AO @ Wo + bo + residual. 64x128 tile, 4 waves, BK=32,
// global_load_lds staging.
// ---------------------------------------------------------------------------
__global__ __launch_bounds__(256, 2) void out_mfma(
    const _Float16* __restrict__ AO, const _Float16* __restrict__ Wt,
    const float* __restrict__ bo, const float* __restrict__ HS,
    float* __restrict__ Outp)
{
    const int mt = blockIdx.x;              // 128
    const int nt = blockIdx.y;              // 4
    const int tid = threadIdx.x;
    const int wave = tid >> 6, lane = tid & 63;
    const int quad = lane >> 4, lm = lane & 15;
    const int wm = (wave & 1) * 32, wn = (wave >> 1) * 64;

    __shared__ _Float16 sA[64 * 32];
    __shared__ _Float16 sB[128 * 32];

    f32x4 acc[2][4];
#pragma unroll
    for (int mf = 0; mf < 2; ++mf)
#pragma unroll
        for (int nf = 0; nf < 4; ++nf) acc[mf][nf] = (f32x4){0.f, 0.f, 0.f, 0.f};

    const int lr = lane >> 2;
    const int lc = (lane & 3) * 8;
    const _Float16* gaA = AO + (size_t)(mt * 64 + wave * 16 + lr) * Cc + lc;
    const _Float16* gaB = Wt + ((size_t)(3 * 512 + nt * 128 + wave * 32 + lr)) * Cc + lc;
    _Float16* ldA = &sA[wave * 512];
    _Float16* ldB = &sB[wave * 1024];

    for (int k0 = 0; k0 < Cc; k0 += 32) {
        __syncthreads();
        gl16(gaA + k0,           ldA);
        gl16(gaB + k0,           ldB);
        gl16(gaB + 16 * Cc + k0, ldB + 512);
        __syncthreads();

        f16x8 ah[2], bh[4];
#pragma unroll
        for (int mf = 0; mf < 2; ++mf)
            ah[mf] = *(const f16x8*)&sA[(wm + mf * 16 + lm) * 32 + quad * 8];
#pragma unroll
        for (int nf = 0; nf < 4; ++nf)
            bh[nf] = *(const f16x8*)&sB[(wn + nf * 16 + lm) * 32 + quad * 8];
#pragma unroll
        for (int mf = 0; mf < 2; ++mf)
#pragma unroll
            for (int nf = 0; nf < 4; ++nf)
                acc[mf][nf] = __builtin_amdgcn_mfma_f32_16x16x32_f16(ah[mf], bh[nf], acc[mf][nf], 0, 0, 0);
    }

#pragma unroll
    for (int mf = 0; mf < 2; ++mf)
#pragma unroll
        for (int r = 0; r < 4; ++r) {
            const size_t m = (size_t)(mt * 64 + wm + mf * 16 + quad * 4 + r);
#pragma unroll
            for (int nf = 0; nf < 4; ++nf) {
                const int col = nt * 128 + wn + nf * 16 + lm;
                Outp[m * Cc + col] = acc[mf][nf][r] + bo[col] + HS[m * Cc + col];
            }
        }
}

// ---------------------------------------------------------------------------
extern "C" void kernel_launch(void* const* d_in, const int* in_sizes, int n_in,
                              void* d_out, int out_size, void* d_ws,
                              size_t ws_size, hipStream_t stream)
{
    const float* HS = (const float*)d_in[0];
    const float* Wq = (const float*)d_in[1];
    const float* Wk = (const float*)d_in[2];
    const float* Wv = (const float*)d_in[3];
    const float* Wo = (const float*)d_in[4];
    const float* bo = (const float*)d_in[5];
    float* out = (float*)d_out;

    const size_t SZ = (size_t)Bb * Tt * Cc;        // 4,194,304 elements
    _Float16* Qf  = (_Float16*)d_ws;
    _Float16* Kf  = Qf + SZ;
    _Float16* VTh = Kf + SZ;
    _Float16* HSh = VTh + SZ;
    _Float16* AO  = HSh + SZ;
    _Float16* Wt  = AO + SZ;                        // 4*Cc*Cc halves
    float* colsum = (float*)(Wt + 4 * Cc * Cc);

    prep<<<2307, 256, 0, stream>>>(Wq, Wk, Wv, Wo, HS, Wt, HSh, colsum);

    qkv_mfma<<<dim3(64, 4, 3), 256, 0, stream>>>(HSh, Wt, Qf, Kf, VTh, colsum);

    attn_mfma<<<dim3(512), 256, 0, stream>>>(Qf, Kf, VTh, colsum, AO);

    out_mfma<<<dim3(128, 4), 256, 0, stream>>>(AO, Wt, bo, HS, out);
}

// Round 16
// 151.476 us; speedup vs baseline: 5.3081x; 1.0952x over previous
//
#include <hip/hip_runtime.h>

#define Tt 2048
#define Cc 512
#define Bb 4
#define BC (Bb * Cc)

typedef __attribute__((ext_vector_type(4))) float f32x4;
typedef __attribute__((ext_vector_type(8))) _Float16 f16x8;
typedef __attribute__((ext_vector_type(4))) _Float16 f16x4;
typedef __attribute__((ext_vector_type(2))) _Float16 f16x2;

// async global->LDS 16B copy: dest = wave-uniform LDS base + lane*16.
__device__ static inline void gl16(const _Float16* g, _Float16* l)
{
    __builtin_amdgcn_global_load_lds(
        (const __attribute__((address_space(1))) void*)g,
        (__attribute__((address_space(3))) void*)l, 16, 0, 0);
}

// ---------------------------------------------------------------------------
// Kernel P: fused prep — blocks [0,2048): HS fp32->fp16; [2048,2304):
// W transpose->Wt fp16; [2304,2307): colsum zero.
// ---------------------------------------------------------------------------
__global__ __launch_bounds__(256) void prep(
    const float* __restrict__ Wq, const float* __restrict__ Wk,
    const float* __restrict__ Wv, const float* __restrict__ Wo,
    const float* __restrict__ HS, _Float16* __restrict__ Wt,
    _Float16* __restrict__ HSh, float* __restrict__ colsum)
{
    const int blk = blockIdx.x;
    const int tid = threadIdx.x;
    __shared__ float tile[64][65];

    if (blk < 2048) {
        const size_t i = ((size_t)blk * 256 + tid) * 8;
        float4 a = *(const float4*)&HS[i];
        float4 b = *(const float4*)&HS[i + 4];
        f16x8 o;
        o[0] = (_Float16)a.x; o[1] = (_Float16)a.y;
        o[2] = (_Float16)a.z; o[3] = (_Float16)a.w;
        o[4] = (_Float16)b.x; o[5] = (_Float16)b.y;
        o[6] = (_Float16)b.z; o[7] = (_Float16)b.w;
        *(f16x8*)&HSh[i] = o;
    } else if (blk < 2304) {
        const int lb = blk - 2048;
        const int z = lb >> 6, x = lb & 63;
        const float* W = (z == 0) ? Wq : (z == 1) ? Wk : (z == 2) ? Wv : Wo;
        const int k0 = (x >> 3) * 64, n0 = (x & 7) * 64;
#pragma unroll
        for (int i = 0; i < 4; ++i) {
            const int idx = i * 256 + tid;
            const int kr = idx >> 4, c4 = idx & 15;
            float4 v = *(const float4*)&W[(size_t)(k0 + kr) * Cc + n0 + c4 * 4];
            tile[kr][c4 * 4 + 0] = v.x; tile[kr][c4 * 4 + 1] = v.y;
            tile[kr][c4 * 4 + 2] = v.z; tile[kr][c4 * 4 + 3] = v.w;
        }
        __syncthreads();
#pragma unroll
        for (int i = 0; i < 4; ++i) {
            const int idx = i * 256 + tid;
            const int nr = idx >> 4, k4 = idx & 15;
            f16x4 o;
            o[0] = (_Float16)tile[k4 * 4 + 0][nr];
            o[1] = (_Float16)tile[k4 * 4 + 1][nr];
            o[2] = (_Float16)tile[k4 * 4 + 2][nr];
            o[3] = (_Float16)tile[k4 * 4 + 3][nr];
            *(f16x4*)&Wt[((size_t)(z * 512 + n0 + nr)) * Cc + k0 + k4 * 4] = o;
        }
    } else {
        const int i = (blk - 2304) * 2048 + tid * 8;
        *(f32x4*)&colsum[i]     = (f32x4){0.f, 0.f, 0.f, 0.f};
        *(f32x4*)&colsum[i + 4] = (f32x4){0.f, 0.f, 0.f, 0.f};
    }
}

// ---------------------------------------------------------------------------
// Kernel 1: QKV GEMM, fp16 MFMA, 128x128 tile, 4 waves, BK=32,
// global_load_lds staging. Epilogue: Q/K fp16 store; V (z==2) is written
// DIRECTLY as VT (transposed + kappa key-permutation) via an LDS bounce.
// All z accumulate per-(b,channel) sum-of-squares.
// ---------------------------------------------------------------------------
__global__ __launch_bounds__(256, 3) void qkv_mfma(
    const _Float16* __restrict__ HSh, const _Float16* __restrict__ Wt,
    _Float16* __restrict__ Qf, _Float16* __restrict__ Kf,
    _Float16* __restrict__ VTh, float* __restrict__ colsum)
{
    const int mt = blockIdx.x;              // 64
    const int nt = blockIdx.y;              // 4
    const int z  = blockIdx.z;              // 3

    const int tid = threadIdx.x;
    const int wave = tid >> 6, lane = tid & 63;
    const int quad = lane >> 4, lm = lane & 15;
    const int wm = (wave & 1) * 64, wn = (wave >> 1) * 64;

    __shared__ _Float16 smem[128 * 136];    // 34.8 KB
    _Float16* sA = smem;                    // 128*32
    _Float16* sB = smem + 128 * 32;         // 128*32

    f32x4 acc[4][4];
#pragma unroll
    for (int mf = 0; mf < 4; ++mf)
#pragma unroll
        for (int nf = 0; nf < 4; ++nf) acc[mf][nf] = (f32x4){0.f, 0.f, 0.f, 0.f};

    const int lr = lane >> 2;
    const int lc = (lane & 3) * 8;
    const _Float16* gaA = HSh + (size_t)(mt * 128 + wave * 32 + lr) * Cc + lc;
    const _Float16* gaB = Wt + ((size_t)(z * 512 + nt * 128 + wave * 32 + lr)) * Cc + lc;
    _Float16* ldA = &sA[wave * 1024];
    _Float16* ldB = &sB[wave * 1024];

    for (int k0 = 0; k0 < Cc; k0 += 32) {
        __syncthreads();
        gl16(gaA + k0,            ldA);
        gl16(gaA + 16 * Cc + k0,  ldA + 512);
        gl16(gaB + k0,            ldB);
        gl16(gaB + 16 * Cc + k0,  ldB + 512);
        __syncthreads();

        f16x8 ah[4], bh[4];
#pragma unroll
        for (int mf = 0; mf < 4; ++mf)
            ah[mf] = *(const f16x8*)&sA[(wm + mf * 16 + lm) * 32 + quad * 8];
#pragma unroll
        for (int nf = 0; nf < 4; ++nf)
            bh[nf] = *(const f16x8*)&sB[(wn + nf * 16 + lm) * 32 + quad * 8];
#pragma unroll
        for (int mf = 0; mf < 4; ++mf)
#pragma unroll
            for (int nf = 0; nf < 4; ++nf)
                acc[mf][nf] = __builtin_amdgcn_mfma_f32_16x16x32_f16(ah[mf], bh[nf], acc[mf][nf], 0, 0, 0);
    }

    const int bidx = mt >> 4;

    // ---- colsum (all z) + Q/K store (z < 2)
    _Float16* Out = (z == 0) ? Qf : Kf;
#pragma unroll
    for (int nf = 0; nf < 4; ++nf) {
        float cs = 0.f;
#pragma unroll
        for (int mf = 0; mf < 4; ++mf)
#pragma unroll
            for (int r = 0; r < 4; ++r) {
                const float v = acc[mf][nf][r];
                cs += v * v;
                if (z < 2) {
                    const size_t idx =
                        (size_t)(mt * 128 + wm + mf * 16 + quad * 4 + r) * Cc +
                        nt * 128 + wn + nf * 16 + lm;
                    Out[idx] = (_Float16)v;
                }
            }
        cs += __shfl_xor(cs, 16, 64);
        cs += __shfl_xor(cs, 32, 64);
        if (lane < 16)
            atomicAdd(&colsum[(size_t)z * BC + bidx * Cc + nt * 128 + wn + nf * 16 + lane], cs);
    }

    // ---- z == 2: write V transposed (VT[b][c][t'], kappa-permuted t) via LDS
    if (z == 2) {
        __syncthreads();            // staging done; reuse smem as TL[c][t']
        // phase A: scatter acc -> TL[c][tperm], stride 136 halves
#pragma unroll
        for (int nf = 0; nf < 4; ++nf) {
            const int c = wn + nf * 16 + lm;
#pragma unroll
            for (int mf = 0; mf < 4; ++mf) {
                const int m0 = wm + mf * 16 + quad * 4;     // +r, r=0..3
                const int tl = m0 & 63;
                const int u = tl >> 3, j0 = tl & 7;
                const int p0 = ((u >> 2) & 1) * 32 + (u & 1) * 16 +
                               ((u >> 1) & 1) * 4 + ((j0 >= 4) ? 8 : 0);
                const int tperm = (m0 & 64) + p0;
                f16x4 pk;
#pragma unroll
                for (int r = 0; r < 4; ++r) pk[r] = (_Float16)acc[mf][nf][r];
                *(f16x4*)&smem[c * 136 + tperm] = pk;
            }
        }
        __syncthreads();
        // phase B: coalesced f16x8 stores to VT
        const int b = mt >> 4;
        const int tbase = (mt & 15) * 128;
#pragma unroll
        for (int i = 0; i < 8; ++i) {
            const int idx = i * 256 + tid;
            const int cr = idx >> 4, t8 = (idx & 15) * 8;
            f16x8 v = *(const f16x8*)&smem[cr * 136 + t8];
            *(f16x8*)&VTh[((size_t)(b * Cc) + nt * 128 + cr) * Tt + tbase + t8] = v;
        }
    }
}

// ---------------------------------------------------------------------------
// Kernel 4: fp16 MFMA flash attention (best measured: 47.2 us). 4 waves,
// 32 q/wave, BK=64 double-buffered reg staging, cross-iteration pipeline
// (QK(kt) | PV(kt-1) | exp(kt)), P in regs via pre-permuted VT, l via
// ones-MFMA, setprio on MFMA clusters, XCD-local 1-D grid.
// inv_norm fused: iq/ik/iv computed inline from colsum (rsqrt).
// ---------------------------------------------------------------------------
#define LSTR 72

__global__ __launch_bounds__(256, 3) void attn_mfma(
    const _Float16* __restrict__ Qf, const _Float16* __restrict__ Kf,
    const _Float16* __restrict__ VT, const float* __restrict__ colsum,
    _Float16* __restrict__ AO)
{
    const int bid = blockIdx.x;           // 512
    const int qt = bid >> 5;              // 16
    const int bh = bid & 31;              // 32 (bid%8 == bh%8 -> XCD locality)
    const int b = bh >> 3, h = bh & 7;
    const int tid = threadIdx.x;
    const int wave = tid >> 6, lane = tid & 63;
    const int quad = lane >> 4, lm = lane & 15;
    const float invT = 1.0f / Tt;

    __shared__ _Float16 sK[2][64 * LSTR];
    __shared__ _Float16 sVT[2][64 * LSTR];

    // ---- per-channel scale iq*ik*0.125*log2(e), computed from colsum inline
    float ss[2][8];
    {
        const float* csq = colsum + b * Cc + h * 64;
        const float* csk = colsum + BC + b * Cc + h * 64;
#pragma unroll
        for (int ks = 0; ks < 2; ++ks) {
            const int d0 = ks * 32 + quad * 8;
#pragma unroll
            for (int j = 0; j < 8; ++j) {
                const float iq = rsqrtf(csq[d0 + j] * invT + 1e-4f);
                const float ik = rsqrtf(csk[d0 + j] * invT + 1e-4f);
                ss[ks][j] = iq * ik * 0.18033688011f;
            }
        }
    }

    // ---- Q fragments (B-operand: n=lm=query, k=quad*8+j)
    f16x8 qb[2][2];
    {
#pragma unroll
        for (int qf = 0; qf < 2; ++qf) {
            const int row = qt * 128 + wave * 32 + qf * 16 + lm;
#pragma unroll
            for (int ks = 0; ks < 2; ++ks) {
                const int d0 = ks * 32 + quad * 8;
                f16x8 qv = *(const f16x8*)&Qf[(size_t)(b * Tt + row) * Cc + h * 64 + d0];
#pragma unroll
                for (int j = 0; j < 8; ++j)
                    qb[qf][ks][j] = (_Float16)((float)qv[j] * ss[ks][j]);
            }
        }
    }

    f32x4 o[4][2];
#pragma unroll
    for (int cf = 0; cf < 4; ++cf)
#pragma unroll
        for (int qf = 0; qf < 2; ++qf) o[cf][qf] = (f32x4){0.f, 0.f, 0.f, 0.f};
    f32x4 ol[2];
#pragma unroll
    for (int qf = 0; qf < 2; ++qf) ol[qf] = (f32x4){0.f, 0.f, 0.f, 0.f};
    f16x8 ones;
#pragma unroll
    for (int j = 0; j < 8; ++j) ones[j] = (_Float16)1.0f;

    f16x8 pb[2][2];
#pragma unroll
    for (int qf = 0; qf < 2; ++qf)
#pragma unroll
        for (int ks = 0; ks < 2; ++ks)
#pragma unroll
            for (int j = 0; j < 8; ++j) pb[qf][ks][j] = (_Float16)0.0f;

    const int sr0 = tid >> 3, sc0 = (tid & 7) * 8;
    const int sr1 = sr0 + 32;
    const _Float16* gK = Kf + (size_t)b * Tt * Cc + h * 64;
    const _Float16* gV = VT + ((size_t)b * Cc + h * 64) * Tt;

    f16x8 rk0, rk1, rv0, rv1;
    {
        rk0 = *(const f16x8*)&gK[(size_t)sr0 * Cc + sc0];
        rk1 = *(const f16x8*)&gK[(size_t)sr1 * Cc + sc0];
        rv0 = *(const f16x8*)&gV[(size_t)sr0 * Tt + sc0];
        rv1 = *(const f16x8*)&gV[(size_t)sr1 * Tt + sc0];
    }

#pragma unroll 2
    for (int kt = 0; kt < 32; ++kt) {
        const int cur = kt & 1, prv = cur ^ 1;
        _Float16* sKc = sK[cur];
        _Float16* sVc = sVT[cur];

        __syncthreads();
        *(f16x8*)&sKc[sr0 * LSTR + sc0] = rk0;
        *(f16x8*)&sKc[sr1 * LSTR + sc0] = rk1;
        *(f16x8*)&sVc[sr0 * LSTR + sc0] = rv0;
        *(f16x8*)&sVc[sr1 * LSTR + sc0] = rv1;
        __syncthreads();

        if (kt < 31) {
            const int t0 = (kt + 1) * 64;
            rk0 = *(const f16x8*)&gK[(size_t)(t0 + sr0) * Cc + sc0];
            rk1 = *(const f16x8*)&gK[(size_t)(t0 + sr1) * Cc + sc0];
            rv0 = *(const f16x8*)&gV[(size_t)sr0 * Tt + t0 + sc0];
            rv1 = *(const f16x8*)&gV[(size_t)sr1 * Tt + t0 + sc0];
        }

        // ---- S^T(kt) = K Q^T
        f32x4 st[4][2];
#pragma unroll
        for (int kf = 0; kf < 4; ++kf)
#pragma unroll
            for (int qf = 0; qf < 2; ++qf) st[kf][qf] = (f32x4){0.f, 0.f, 0.f, 0.f};
#pragma unroll
        for (int ks = 0; ks < 2; ++ks) {
            f16x8 ka[4];
#pragma unroll
            for (int kf = 0; kf < 4; ++kf)
                ka[kf] = *(const f16x8*)&sKc[(kf * 16 + lm) * LSTR + ks * 32 + quad * 8];
            __builtin_amdgcn_s_setprio(1);
#pragma unroll
            for (int kf = 0; kf < 4; ++kf)
#pragma unroll
                for (int qf = 0; qf < 2; ++qf)
                    st[kf][qf] = __builtin_amdgcn_mfma_f32_16x16x32_f16(ka[kf], qb[qf][ks], st[kf][qf], 0, 0, 0);
            __builtin_amdgcn_s_setprio(0);
        }

        // ---- PV(kt-1): O^T += VT P^T ; l += ones P^T
        if (kt > 0) {
            _Float16* sVp = sVT[prv];
#pragma unroll
            for (int ks = 0; ks < 2; ++ks) {
                f16x8 va[4];
#pragma unroll
                for (int cf = 0; cf < 4; ++cf)
                    va[cf] = *(const f16x8*)&sVp[(cf * 16 + lm) * LSTR + ks * 32 + quad * 8];
                __builtin_amdgcn_s_setprio(1);
#pragma unroll
                for (int cf = 0; cf < 4; ++cf)
#pragma unroll
                    for (int qf = 0; qf < 2; ++qf)
                        o[cf][qf] = __builtin_amdgcn_mfma_f32_16x16x32_f16(va[cf], pb[qf][ks], o[cf][qf], 0, 0, 0);
#pragma unroll
                for (int qf = 0; qf < 2; ++qf)
                    ol[qf] = __builtin_amdgcn_mfma_f32_16x16x32_f16(ones, pb[qf][ks], ol[qf], 0, 0, 0);
                __builtin_amdgcn_s_setprio(0);
            }
        }

        // ---- p = exp2(s(kt)) -> pb regs
#pragma unroll
        for (int ks = 0; ks < 2; ++ks)
#pragma unroll
            for (int qf = 0; qf < 2; ++qf) {
                const f32x4 a = st[2 * ks][qf];
                const f32x4 c = st[2 * ks + 1][qf];
                const f16x2 l0 = __builtin_bit_cast(f16x2, __builtin_amdgcn_cvt_pkrtz(
                    __builtin_amdgcn_exp2f(a[0]), __builtin_amdgcn_exp2f(a[1])));
                const f16x2 l1 = __builtin_bit_cast(f16x2, __builtin_amdgcn_cvt_pkrtz(
                    __builtin_amdgcn_exp2f(a[2]), __builtin_amdgcn_exp2f(a[3])));
                const f16x2 h0 = __builtin_bit_cast(f16x2, __builtin_amdgcn_cvt_pkrtz(
                    __builtin_amdgcn_exp2f(c[0]), __builtin_amdgcn_exp2f(c[1])));
                const f16x2 h1 = __builtin_bit_cast(f16x2, __builtin_amdgcn_cvt_pkrtz(
                    __builtin_amdgcn_exp2f(c[2]), __builtin_amdgcn_exp2f(c[3])));
                f16x8 p;
                p[0] = l0[0]; p[1] = l0[1]; p[2] = l1[0]; p[3] = l1[1];
                p[4] = h0[0]; p[5] = h0[1]; p[6] = h1[0]; p[7] = h1[1];
                pb[qf][ks] = p;
            }
    }

    // ---- drain PV(31)
    {
        _Float16* sVp = sVT[1];
#pragma unroll
        for (int ks = 0; ks < 2; ++ks) {
            f16x8 va[4];
#pragma unroll
            for (int cf = 0; cf < 4; ++cf)
                va[cf] = *(const f16x8*)&sVp[(cf * 16 + lm) * LSTR + ks * 32 + quad * 8];
#pragma unroll
            for (int cf = 0; cf < 4; ++cf)
#pragma unroll
                for (int qf = 0; qf < 2; ++qf)
                    o[cf][qf] = __builtin_amdgcn_mfma_f32_16x16x32_f16(va[cf], pb[qf][ks], o[cf][qf], 0, 0, 0);
#pragma unroll
            for (int qf = 0; qf < 2; ++qf)
                ol[qf] = __builtin_amdgcn_mfma_f32_16x16x32_f16(ones, pb[qf][ks], ol[qf], 0, 0, 0);
        }
    }

    // ---- epilogue: il from ones-MFMA, iv inline from colsum
    float il[2];
#pragma unroll
    for (int qf = 0; qf < 2; ++qf) il[qf] = 1.0f / ol[qf][0];
    const float* csv = colsum + 2 * BC + b * Cc + h * 64;
    float iv[4][4];
#pragma unroll
    for (int cf = 0; cf < 4; ++cf) {
        float4 t = *(const float4*)&csv[cf * 16 + quad * 4];
        iv[cf][0] = rsqrtf(t.x * invT + 1e-4f);
        iv[cf][1] = rsqrtf(t.y * invT + 1e-4f);
        iv[cf][2] = rsqrtf(t.z * invT + 1e-4f);
        iv[cf][3] = rsqrtf(t.w * invT + 1e-4f);
    }
#pragma unroll
    for (int qf = 0; qf < 2; ++qf) {
        const size_t row = (size_t)(b * Tt + qt * 128 + wave * 32 + qf * 16 + lm);
#pragma unroll
        for (int cf = 0; cf < 4; ++cf) {
            f16x4 pk;
#pragma unroll
            for (int r = 0; r < 4; ++r)
                pk[r] = (_Float16)(o[cf][qf][r] * il[qf] * iv[cf][r]);
            *(f16x4*)&AO[row * Cc + h * 64 + cf * 16 + quad * 4] = pk;
        }
    }
}

// ---------------------------------------------------------------------------
// Kernel 5: out = AO @ Wo + bo + residual. 64x128 tile, 4 waves, BK=32,
// global_load_lds staging.
// ---------------------------------------------------------------------------
__global__ __launch_bounds__(256, 2) void out_mfma(
    const _Float16* __restrict__ AO, const _Float16* __restrict__ Wt,
    const float* __restrict__ bo, const float* __restrict__ HS,
    float* __restrict__ Outp)
{
    const int mt = blockIdx.x;              // 128
    const int nt = blockIdx.y;              // 4
    const int tid = threadIdx.x;
    const int wave = tid >> 6, lane = tid & 63;
    const int quad = lane >> 4, lm = lane & 15;
    const int wm = (wave & 1) * 32, wn = (wave >> 1) * 64;

    __shared__ _Float16 sA[64 * 32];
    __shared__ _Float16 sB[128 * 32];

    f32x4 acc[2][4];
#pragma unroll
    for (int mf = 0; mf < 2; ++mf)
#pragma unroll
        for (int nf = 0; nf < 4; ++nf) acc[mf][nf] = (f32x4){0.f, 0.f, 0.f, 0.f};

    const int lr = lane >> 2;
    const int lc = (lane & 3) * 8;
    const _Float16* gaA = AO + (size_t)(mt * 64 + wave * 16 + lr) * Cc + lc;
    const _Float16* gaB = Wt + ((size_t)(3 * 512 + nt * 128 + wave * 32 + lr)) * Cc + lc;
    _Float16* ldA = &sA[wave * 512];
    _Float16* ldB = &sB[wave * 1024];

    for (int k0 = 0; k0 < Cc; k0 += 32) {
        __syncthreads();
        gl16(gaA + k0,           ldA);
        gl16(gaB + k0,           ldB);
        gl16(gaB + 16 * Cc + k0, ldB + 512);
        __syncthreads();

        f16x8 ah[2], bh[4];
#pragma unroll
        for (int mf = 0; mf < 2; ++mf)
            ah[mf] = *(const f16x8*)&sA[(wm + mf * 16 + lm) * 32 + quad * 8];
#pragma unroll
        for (int nf = 0; nf < 4; ++nf)
            bh[nf] = *(const f16x8*)&sB[(wn + nf * 16 + lm) * 32 + quad * 8];
#pragma unroll
        for (int mf = 0; mf < 2; ++mf)
#pragma unroll
            for (int nf = 0; nf < 4; ++nf)
                acc[mf][nf] = __builtin_amdgcn_mfma_f32_16x16x32_f16(ah[mf], bh[nf], acc[mf][nf], 0, 0, 0);
    }

#pragma unroll
    for (int mf = 0; mf < 2; ++mf)
#pragma unroll
        for (int r = 0; r < 4; ++r) {
            const size_t m = (size_t)(mt * 64 + wm + mf * 16 + quad * 4 + r);
#pragma unroll
            for (int nf = 0; nf < 4; ++nf) {
                const int col = nt * 128 + wn + nf * 16 + lm;
                Outp[m * Cc + col] = acc[mf][nf][r] + bo[col] + HS[m * Cc + col];
            }
        }
}

// ---------------------------------------------------------------------------
extern "C" void kernel_launch(void* const* d_in, const int* in_sizes, int n_in,
                              void* d_out, int out_size, void* d_ws,
                              size_t ws_size, hipStream_t stream)
{
    const float* HS = (const float*)d_in[0];
    const float* Wq = (const float*)d_in[1];
    const float* Wk = (const float*)d_in[2];
    const float* Wv = (const float*)d_in[3];
    const float* Wo = (const float*)d_in[4];
    const float* bo = (const float*)d_in[5];
    float* out = (float*)d_out;

    const size_t SZ = (size_t)Bb * Tt * Cc;        // 4,194,304 elements
    _Float16* Qf  = (_Float16*)d_ws;
    _Float16* Kf  = Qf + SZ;
    _Float16* VTh = Kf + SZ;
    _Float16* HSh = VTh + SZ;
    _Float16* AO  = HSh + SZ;
    _Float16* Wt  = AO + SZ;                        // 4*Cc*Cc halves
    float* colsum = (float*)(Wt + 4 * Cc * Cc);

    prep<<<2307, 256, 0, stream>>>(Wq, Wk, Wv, Wo, HS, Wt, HSh, colsum);

    qkv_mfma<<<dim3(64, 4, 3), 256, 0, stream>>>(HSh, Wt, Qf, Kf, VTh, colsum);

    attn_mfma<<<dim3(512), 256, 0, stream>>>(Qf, Kf, VTh, colsum, AO);

    out_mfma<<<dim3(128, 4), 256, 0, stream>>>(AO, Wt, bo, HS, out);
}